// Round 1
// baseline (1016.135 us; speedup 1.0000x reference)
//
#include <hip/hip_runtime.h>
#include <hip/hip_bf16.h>
#include <float.h>

// ---------------------------------------------------------------------------
// ImprovedTransformerGNN: fp32 end-to-end (threshold is fp32-tight; no MFMA
// fp32 path exists on CDNA4, so matmuls run on the vector ALU).
// Sizes: N=50000 nodes, E=600000 edges, H=128, IN=128, C=4, L=3, G=128.
// ---------------------------------------------------------------------------

#define H128 128
#define GGRAPHS 128

__device__ __forceinline__ float gelu_f(float x) {
    return 0.5f * x * (1.0f + erff(x * 0.7071067811865476f));
}

static constexpr float BNS_F = 0.99999500003749968f;  // 1/sqrt(1+1e-5)

// ---------------------------------------------------------------------------
// Fused GEMM: Y[nrows,M] = act( (X[nrows,128] @ W[128,M]) * colscale + colbias ) (+ resid)
// Block: 256 threads, 64 rows. Thread (rowgrp=tid>>4, colgrp=tid&15) computes
// 4 rows x CPT cols. Column split: cols [4c..4c+3] and [64+4c..64+4c+3] so the
// 16 float4 LDS readers per wave cover all 8 bank-quads (conflict-free).
// In-place X==Y is safe: each wave reads only the rows it writes, and writes
// happen after the k-loop (lockstep within wave).
// ---------------------------------------------------------------------------
template<int M, bool DO_BN, bool DO_GELU, bool DO_RES>
__global__ __launch_bounds__(256, 2)
void gemm_fused(const float* __restrict__ X, const float* __restrict__ W,
                const float* __restrict__ bias, const float* __restrict__ gam,
                const float* __restrict__ beta, const float* __restrict__ resid,
                float* __restrict__ Y, int nrows)
{
    constexpr int CPT = M / 16;   // 8 (M=128) or 4 (M=64)
    constexpr int NF4 = M / 4;    // float4 per k-row
    __shared__ float4 Ws[128 * NF4];

    const int tid = threadIdx.x;
    const float4* W4 = reinterpret_cast<const float4*>(W);
#pragma unroll
    for (int i = 0; i < (128 * NF4) / 256; ++i)
        Ws[tid + i * 256] = W4[tid + i * 256];
    __syncthreads();

    const int colgrp = tid & 15;
    const int rowgrp = tid >> 4;
    const int r0 = blockIdx.x * 64 + rowgrp * 4;

    float acc[4][CPT];
#pragma unroll
    for (int i = 0; i < 4; ++i)
#pragma unroll
        for (int j = 0; j < CPT; ++j) acc[i][j] = 0.f;

    const float4* xp[4];
#pragma unroll
    for (int i = 0; i < 4; ++i) {
        int r = r0 + i; if (r >= nrows) r = nrows - 1;
        xp[i] = reinterpret_cast<const float4*>(X + (size_t)r * 128);
    }
    float4 xv[4];
#pragma unroll
    for (int i = 0; i < 4; ++i) xv[i] = xp[i][0];

    for (int k4 = 0; k4 < 32; ++k4) {
        float4 xn[4];
#pragma unroll
        for (int i = 0; i < 4; ++i) xn[i] = xv[i];
        if (k4 < 31) {
#pragma unroll
            for (int i = 0; i < 4; ++i) xn[i] = xp[i][k4 + 1];
        }
#pragma unroll
        for (int kk = 0; kk < 4; ++kk) {
            const int k = k4 * 4 + kk;
            const float4 w0 = Ws[k * NF4 + colgrp];
            float4 w1;
            if (CPT == 8) w1 = Ws[k * NF4 + 16 + colgrp];
#pragma unroll
            for (int i = 0; i < 4; ++i) {
                const float xs = reinterpret_cast<const float*>(&xv[i])[kk];
                acc[i][0] = fmaf(xs, w0.x, acc[i][0]);
                acc[i][1] = fmaf(xs, w0.y, acc[i][1]);
                acc[i][2] = fmaf(xs, w0.z, acc[i][2]);
                acc[i][3] = fmaf(xs, w0.w, acc[i][3]);
                if (CPT == 8) {
                    acc[i][4] = fmaf(xs, w1.x, acc[i][4]);
                    acc[i][5] = fmaf(xs, w1.y, acc[i][5]);
                    acc[i][6] = fmaf(xs, w1.z, acc[i][6]);
                    acc[i][7] = fmaf(xs, w1.w, acc[i][7]);
                }
            }
        }
#pragma unroll
        for (int i = 0; i < 4; ++i) xv[i] = xn[i];
    }

    // epilogue: per-column scale/bias (BN folded), gelu, residual
    float scA[4], biA[4], scB[4], biB[4];
#pragma unroll
    for (int j = 0; j < 4; ++j) {
        const int c = 4 * colgrp + j;
        if (DO_BN) { float g = gam[c]; scA[j] = g * BNS_F; biA[j] = bias[c] * scA[j] + beta[c]; }
        else       { scA[j] = 1.f;     biA[j] = bias[c]; }
        if (CPT == 8) {
            const int c2 = 64 + 4 * colgrp + j;
            if (DO_BN) { float g = gam[c2]; scB[j] = g * BNS_F; biB[j] = bias[c2] * scB[j] + beta[c2]; }
            else       { scB[j] = 1.f;      biB[j] = bias[c2]; }
        }
    }
#pragma unroll
    for (int i = 0; i < 4; ++i) {
        const int r = r0 + i;
        if (r < nrows) {
            float4 o0; float* o0f = reinterpret_cast<float*>(&o0);
#pragma unroll
            for (int j = 0; j < 4; ++j) {
                float v = acc[i][j] * scA[j] + biA[j];
                if (DO_GELU) v = gelu_f(v);
                if (DO_RES) v += resid[(size_t)r * M + 4 * colgrp + j];
                o0f[j] = v;
            }
            *reinterpret_cast<float4*>(Y + (size_t)r * M + 4 * colgrp) = o0;
            if (CPT == 8) {
                float4 o1; float* o1f = reinterpret_cast<float*>(&o1);
#pragma unroll
                for (int j = 0; j < 4; ++j) {
                    float v = acc[i][4 + j] * scB[j] + biB[j];
                    if (DO_GELU) v = gelu_f(v);
                    if (DO_RES) v += resid[(size_t)r * M + 64 + 4 * colgrp + j];
                    o1f[j] = v;
                }
                *reinterpret_cast<float4*>(Y + (size_t)r * M + 64 + 4 * colgrp) = o1;
            }
        }
    }
}

// ---------------------------------------------------------------------------
// CSR build + degree
// ---------------------------------------------------------------------------
__global__ void count_kernel(const int* __restrict__ dst, int* __restrict__ cnt, int E)
{
    int e = blockIdx.x * 256 + threadIdx.x;
    if (e < E) atomicAdd(&cnt[dst[e]], 1);
}

__global__ void dinv_kernel(const int* __restrict__ cnt, float* __restrict__ dinv, int n)
{
    int i = blockIdx.x * 256 + threadIdx.x;
    if (i < n) dinv[i] = 1.0f / sqrtf((float)cnt[i] + 1.0f);
}

__global__ void scan_kernel(const int* __restrict__ cnt, int* __restrict__ rowptr, int n)
{
    __shared__ int sdata[1024];
    __shared__ int running;
    const int tid = threadIdx.x;
    if (tid == 0) { running = 0; rowptr[0] = 0; }
    __syncthreads();
    for (int base = 0; base < n; base += 1024) {
        const int i = base + tid;
        int v = (i < n) ? cnt[i] : 0;
        sdata[tid] = v;
        __syncthreads();
        for (int off = 1; off < 1024; off <<= 1) {
            int t = (tid >= off) ? sdata[tid - off] : 0;
            __syncthreads();
            sdata[tid] += t;
            __syncthreads();
        }
        const int incl = sdata[tid] + running;
        if (i < n) rowptr[i + 1] = incl;
        __syncthreads();
        if (tid == 1023) running += sdata[1023];
        __syncthreads();
    }
}

__global__ void fill_kernel(const int* __restrict__ src, const int* __restrict__ dst,
                            const float* __restrict__ dinv, const int* __restrict__ rowptr,
                            int* __restrict__ cursor, int* __restrict__ csr_src,
                            float* __restrict__ csr_w, int E)
{
    int e = blockIdx.x * 256 + threadIdx.x;
    if (e < E) {
        const int d = dst[e], s = src[e];
        const int pos = rowptr[d] + atomicAdd(&cursor[d], 1);
        csr_src[pos] = s;
        csr_w[pos] = dinv[s] * dinv[d];
    }
}

// ---------------------------------------------------------------------------
// Aggregation (gather over CSR): ah[n] = h[n]*snorm + sum_e h[src_e]*w_e
// 2 nodes per 256-thread block; coalesced 512B row reads.
// ---------------------------------------------------------------------------
__global__ __launch_bounds__(256)
void agg_kernel(const float* __restrict__ h, const int* __restrict__ csr_src,
                const float* __restrict__ csr_w, const int* __restrict__ rowptr,
                const float* __restrict__ dinv, float* __restrict__ ah, int n)
{
    const int node = blockIdx.x * 2 + (threadIdx.x >> 7);
    if (node >= n) return;
    const int f = threadIdx.x & 127;
    const float di = dinv[node];
    float acc = h[(size_t)node * 128 + f] * (di * di);
    const int beg = rowptr[node], end = rowptr[node + 1];
    for (int s = beg; s < end; ++s) {
        const int sn = csr_src[s];
        const float w = csr_w[s];
        acc = fmaf(h[(size_t)sn * 128 + f], w, acc);
    }
    ah[(size_t)node * 128 + f] = acc;
}

// ---------------------------------------------------------------------------
// attention scalar: aw[n] = tanh(dot(t[n,0:64], Wa2) + ba2); one wave per row
// ---------------------------------------------------------------------------
__global__ void aw_kernel(const float* __restrict__ t, const float* __restrict__ Wa2,
                          const float* __restrict__ ba2, float* __restrict__ aw, int n)
{
    const int row = blockIdx.x * 4 + (threadIdx.x >> 6);
    const int lane = threadIdx.x & 63;
    if (row >= n) return;
    float v = t[(size_t)row * 64 + lane] * Wa2[lane];
#pragma unroll
    for (int off = 32; off > 0; off >>= 1) v += __shfl_xor(v, off);
    if (lane == 0) aw[row] = tanhf(v + ba2[0]);
}

// ---------------------------------------------------------------------------
// batch is sorted: per-graph boundaries via binary search
// ---------------------------------------------------------------------------
__global__ void bounds_kernel(const int* __restrict__ batch, int* __restrict__ bound, int n, int g)
{
    const int t = blockIdx.x * blockDim.x + threadIdx.x;
    if (t > g) return;
    int lo = 0, hi = n;
    while (lo < hi) { int mid = (lo + hi) >> 1; if (batch[mid] < t) lo = mid + 1; else hi = mid; }
    bound[t] = lo;
}

// ---------------------------------------------------------------------------
// fused pooling: mean / max / weighted-sum per graph in one pass
// comb[g, 0:128)=mean, [128:256)=max, [256:384)=mean, [384:512)=wmean
// ---------------------------------------------------------------------------
__global__ void pool_kernel(const float* __restrict__ h, const float* __restrict__ aw,
                            const int* __restrict__ bound, float* __restrict__ comb)
{
    const int g = blockIdx.x;
    const int f = threadIdx.x;  // 128 threads
    const int beg = bound[g], end = bound[g + 1];
    float s = 0.f, m = -FLT_MAX, wsum = 0.f;
    for (int node = beg; node < end; ++node) {
        const float v = h[(size_t)node * 128 + f];
        const float a = aw[node];
        s += v;
        m = fmaxf(m, v);
        wsum = fmaf(v, a, wsum);
    }
    float c = (float)(end - beg);
    if (c < 1.f) c = 1.f;
    comb[(size_t)g * 512 + f]       = s / c;
    comb[(size_t)g * 512 + 128 + f] = m;
    comb[(size_t)g * 512 + 256 + f] = s / c;
    comb[(size_t)g * 512 + 384 + f] = wsum / c;
}

// ---------------------------------------------------------------------------
// small row-GEMM for the classifier head (G=128 rows): one block per row
// ---------------------------------------------------------------------------
template<bool DO_BN, bool DO_GELU>
__global__ void rowgemm(const float* __restrict__ X, const float* __restrict__ W,
                        const float* __restrict__ bias, const float* __restrict__ gam,
                        const float* __restrict__ beta, float* __restrict__ Y,
                        int K, int M)
{
    __shared__ float xs[512];
    const int row = blockIdx.x;
    for (int i = threadIdx.x; i < K; i += blockDim.x) xs[i] = X[(size_t)row * K + i];
    __syncthreads();
    const int c = threadIdx.x;
    if (c < M) {
        float acc = 0.f;
        for (int k = 0; k < K; ++k) acc = fmaf(xs[k], W[(size_t)k * M + c], acc);
        float v;
        if (DO_BN) { const float g = gam[c]; const float sc = g * BNS_F; v = acc * sc + (bias[c] * sc + beta[c]); }
        else       { v = acc + bias[c]; }
        if (DO_GELU) v = gelu_f(v);
        Y[(size_t)row * M + c] = v;
    }
}

// ---------------------------------------------------------------------------
extern "C" void kernel_launch(void* const* d_in, const int* in_sizes, int n_in,
                              void* d_out, int out_size, void* d_ws, size_t ws_size,
                              hipStream_t stream)
{
    const float* x     = (const float*)d_in[0];
    const int*   ei    = (const int*)d_in[1];
    const int*   batch = (const int*)d_in[2];
    const float* W1  = (const float*)d_in[3];
    const float* b1  = (const float*)d_in[4];
    const float* g1  = (const float*)d_in[5];
    const float* be1 = (const float*)d_in[6];
    const float* W2  = (const float*)d_in[7];
    const float* b2  = (const float*)d_in[8];
    const float* g2  = (const float*)d_in[9];
    const float* be2 = (const float*)d_in[10];
    const float* Wg  = (const float*)d_in[11];
    const float* bg  = (const float*)d_in[12];
    const float* gg  = (const float*)d_in[13];
    const float* bgg = (const float*)d_in[14];
    const float* Wa1 = (const float*)d_in[15];
    const float* ba1 = (const float*)d_in[16];
    const float* Wa2 = (const float*)d_in[17];
    const float* ba2 = (const float*)d_in[18];
    const float* Wc1 = (const float*)d_in[19];
    const float* bc1 = (const float*)d_in[20];
    const float* gc1 = (const float*)d_in[21];
    const float* bec1= (const float*)d_in[22];
    const float* Wc2 = (const float*)d_in[23];
    const float* bc2 = (const float*)d_in[24];
    const float* gc2 = (const float*)d_in[25];
    const float* bec2= (const float*)d_in[26];
    const float* Wc3 = (const float*)d_in[27];
    const float* bc3 = (const float*)d_in[28];
    const float* gc3 = (const float*)d_in[29];
    const float* bec3= (const float*)d_in[30];
    const float* Wc4 = (const float*)d_in[31];
    const float* bc4 = (const float*)d_in[32];
    float* out = (float*)d_out;

    const int N = in_sizes[0] / 128;
    const int E = in_sizes[1] / 2;
    const int G = GGRAPHS;

    // workspace carve-up
    size_t off = 0;
    auto alloc = [&](size_t bytes) -> void* {
        void* p = (char*)d_ws + off;
        off += (bytes + 255) & ~(size_t)255;
        return p;
    };
    float* hA     = (float*)alloc((size_t)N * 128 * 4);
    float* hB     = (float*)alloc((size_t)N * 128 * 4);   // also aliases t [N,64]
    float* aw     = (float*)alloc((size_t)N * 4);
    float* dinv   = (float*)alloc((size_t)N * 4);
    int*   cnt    = (int*)alloc((size_t)N * 4);
    int*   cursor = (int*)alloc((size_t)N * 4);
    int*   rowptr = (int*)alloc((size_t)(N + 1) * 4);
    int*   csr_src= (int*)alloc((size_t)E * 4);
    float* csr_w  = (float*)alloc((size_t)E * 4);
    int*   bound  = (int*)alloc((size_t)(G + 1) * 4);
    float* comb   = (float*)alloc((size_t)G * 512 * 4);
    float* z1     = (float*)alloc((size_t)G * 256 * 4);
    float* z2     = (float*)alloc((size_t)G * 128 * 4);
    float* z3     = (float*)alloc((size_t)G * 64 * 4);
    (void)ws_size;

    const int* e_src = ei;
    const int* e_dst = ei + E;

    // ---- CSR build over dst (reused by all 3 GCN layers) ----
    hipMemsetAsync(cnt, 0, (size_t)N * 4, stream);
    hipMemsetAsync(cursor, 0, (size_t)N * 4, stream);
    count_kernel<<<(E + 255) / 256, 256, 0, stream>>>(e_dst, cnt, E);
    dinv_kernel<<<(N + 255) / 256, 256, 0, stream>>>(cnt, dinv, N);
    scan_kernel<<<1, 1024, 0, stream>>>(cnt, rowptr, N);
    fill_kernel<<<(E + 255) / 256, 256, 0, stream>>>(e_src, e_dst, dinv, rowptr, cursor,
                                                     csr_src, csr_w, E);

    const int gblocks = (N + 63) / 64;

    // ---- input projection ----
    gemm_fused<128, true, true, false><<<gblocks, 256, 0, stream>>>(x,  W1, b1, g1, be1, nullptr, hA, N);
    gemm_fused<128, true, true, false><<<gblocks, 256, 0, stream>>>(hA, W2, b2, g2, be2, nullptr, hA, N);

    // ---- GCN layers: aggregate-then-transform (linearity) ----
    for (int l = 0; l < 3; ++l) {
        agg_kernel<<<(N + 1) / 2, 256, 0, stream>>>(hA, csr_src, csr_w, rowptr, dinv, hB, N);
        gemm_fused<128, true, true, true><<<gblocks, 256, 0, stream>>>(
            hB, Wg + (size_t)l * 128 * 128, bg + (size_t)l * 128,
            gg + (size_t)l * 128, bgg + (size_t)l * 128, hA, hA, N);
    }

    // ---- attention weights ----
    gemm_fused<64, false, true, false><<<gblocks, 256, 0, stream>>>(hA, Wa1, ba1, nullptr, nullptr, nullptr, hB, N);
    aw_kernel<<<(N + 3) / 4, 256, 0, stream>>>(hB, Wa2, ba2, aw, N);

    // ---- pooling ----
    bounds_kernel<<<1, 256, 0, stream>>>(batch, bound, N, G);
    pool_kernel<<<G, 128, 0, stream>>>(hA, aw, bound, comb);

    // ---- classifier head ----
    rowgemm<true, true><<<G, 256, 0, stream>>>(comb, Wc1, bc1, gc1, bec1, z1, 512, 256);
    rowgemm<true, true><<<G, 128, 0, stream>>>(z1, Wc2, bc2, gc2, bec2, z2, 256, 128);
    rowgemm<true, true><<<G, 64, 0, stream>>>(z2, Wc3, bc3, gc3, bec3, z3, 128, 64);
    rowgemm<false, false><<<G, 64, 0, stream>>>(z3, Wc4, bc4, nullptr, nullptr, out, 64, 4);
}

// Round 2
// 643.256 us; speedup vs baseline: 1.5797x; 1.5797x over previous
//
#include <hip/hip_runtime.h>
#include <hip/hip_bf16.h>
#include <float.h>

// ---------------------------------------------------------------------------
// ImprovedTransformerGNN: fp32 end-to-end.
// N=50000, E=600000, H=128, IN=128, C=4, L=3, G=128.
// R2: latency-optimized agg (float4 + 4-edge ILP), 2-stage pool, 3-phase scan,
//     aw fused into the M=64 GEMM epilogue.
// ---------------------------------------------------------------------------

#define GGRAPHS 128
#define POOL_NC 16

__device__ __forceinline__ float gelu_f(float x) {
    return 0.5f * x * (1.0f + erff(x * 0.7071067811865476f));
}

static constexpr float BNS_F = 0.99999500003749968f;  // 1/sqrt(1+1e-5)

// ---------------------------------------------------------------------------
// Fused GEMM: Y[nrows,M] = act( (X[nrows,128] @ W[128,M]) * colscale + colbias ) (+ resid)
// Block: 256 threads, 64 rows. Thread (rowgrp=tid>>4, colgrp=tid&15) computes
// 4 rows x CPT cols. In-place X==Y safe (wave reads only its own rows; writes
// after the k-loop). DO_AW: skip Y store, emit aw[r]=tanh(gelu(row)@Wa2+ba2).
// ---------------------------------------------------------------------------
template<int M, bool DO_BN, bool DO_GELU, bool DO_RES, bool DO_AW>
__global__ __launch_bounds__(256, 4)
void gemm_fused(const float* __restrict__ X, const float* __restrict__ W,
                const float* __restrict__ bias, const float* __restrict__ gam,
                const float* __restrict__ beta, const float* __restrict__ resid,
                float* __restrict__ Y, const float* __restrict__ Wa2,
                const float* __restrict__ ba2, float* __restrict__ awout, int nrows)
{
    constexpr int CPT = M / 16;   // 8 (M=128) or 4 (M=64)
    constexpr int NF4 = M / 4;    // float4 per k-row
    __shared__ float4 Ws[128 * NF4];

    const int tid = threadIdx.x;
    const float4* W4 = reinterpret_cast<const float4*>(W);
#pragma unroll
    for (int i = 0; i < (128 * NF4) / 256; ++i)
        Ws[tid + i * 256] = W4[tid + i * 256];
    __syncthreads();

    const int colgrp = tid & 15;
    const int rowgrp = tid >> 4;
    const int r0 = blockIdx.x * 64 + rowgrp * 4;

    float acc[4][CPT];
#pragma unroll
    for (int i = 0; i < 4; ++i)
#pragma unroll
        for (int j = 0; j < CPT; ++j) acc[i][j] = 0.f;

    const float4* xp[4];
#pragma unroll
    for (int i = 0; i < 4; ++i) {
        int r = r0 + i; if (r >= nrows) r = nrows - 1;
        xp[i] = reinterpret_cast<const float4*>(X + (size_t)r * 128);
    }
    float4 xv[4];
#pragma unroll
    for (int i = 0; i < 4; ++i) xv[i] = xp[i][0];

    for (int k4 = 0; k4 < 32; ++k4) {
        float4 xn[4];
#pragma unroll
        for (int i = 0; i < 4; ++i) xn[i] = xv[i];
        if (k4 < 31) {
#pragma unroll
            for (int i = 0; i < 4; ++i) xn[i] = xp[i][k4 + 1];
        }
#pragma unroll
        for (int kk = 0; kk < 4; ++kk) {
            const int k = k4 * 4 + kk;
            const float4 w0 = Ws[k * NF4 + colgrp];
            float4 w1;
            if (CPT == 8) w1 = Ws[k * NF4 + 16 + colgrp];
#pragma unroll
            for (int i = 0; i < 4; ++i) {
                const float xs = reinterpret_cast<const float*>(&xv[i])[kk];
                acc[i][0] = fmaf(xs, w0.x, acc[i][0]);
                acc[i][1] = fmaf(xs, w0.y, acc[i][1]);
                acc[i][2] = fmaf(xs, w0.z, acc[i][2]);
                acc[i][3] = fmaf(xs, w0.w, acc[i][3]);
                if (CPT == 8) {
                    acc[i][4] = fmaf(xs, w1.x, acc[i][4]);
                    acc[i][5] = fmaf(xs, w1.y, acc[i][5]);
                    acc[i][6] = fmaf(xs, w1.z, acc[i][6]);
                    acc[i][7] = fmaf(xs, w1.w, acc[i][7]);
                }
            }
        }
#pragma unroll
        for (int i = 0; i < 4; ++i) xv[i] = xn[i];
    }

    // epilogue: per-column scale/bias (BN folded), gelu, residual / aw
    float scA[4], biA[4], scB[4], biB[4];
#pragma unroll
    for (int j = 0; j < 4; ++j) {
        const int c = 4 * colgrp + j;
        if (DO_BN) { float g = gam[c]; scA[j] = g * BNS_F; biA[j] = bias[c] * scA[j] + beta[c]; }
        else       { scA[j] = 1.f;     biA[j] = bias[c]; }
        if (CPT == 8) {
            const int c2 = 64 + 4 * colgrp + j;
            if (DO_BN) { float g = gam[c2]; scB[j] = g * BNS_F; biB[j] = bias[c2] * scB[j] + beta[c2]; }
            else       { scB[j] = 1.f;      biB[j] = bias[c2]; }
        }
    }

    if (DO_AW) {
        // aw[r] = tanh( gelu(row) . Wa2 + ba2 ); row spread over 16 colgrps
        float wa[4];
#pragma unroll
        for (int j = 0; j < 4; ++j) wa[j] = Wa2[4 * colgrp + j];
        const float ba2v = ba2[0];
#pragma unroll
        for (int i = 0; i < 4; ++i) {
            float p = 0.f;
#pragma unroll
            for (int j = 0; j < 4; ++j) {
                float v = acc[i][j] * scA[j] + biA[j];
                if (DO_GELU) v = gelu_f(v);
                p = fmaf(v, wa[j], p);
            }
            p += __shfl_xor(p, 1);
            p += __shfl_xor(p, 2);
            p += __shfl_xor(p, 4);
            p += __shfl_xor(p, 8);
            const int r = r0 + i;
            if (colgrp == 0 && r < nrows) awout[r] = tanhf(p + ba2v);
        }
        return;
    }

#pragma unroll
    for (int i = 0; i < 4; ++i) {
        const int r = r0 + i;
        if (r < nrows) {
            float4 o0; float* o0f = reinterpret_cast<float*>(&o0);
#pragma unroll
            for (int j = 0; j < 4; ++j) {
                float v = acc[i][j] * scA[j] + biA[j];
                if (DO_GELU) v = gelu_f(v);
                if (DO_RES) v += resid[(size_t)r * M + 4 * colgrp + j];
                o0f[j] = v;
            }
            *reinterpret_cast<float4*>(Y + (size_t)r * M + 4 * colgrp) = o0;
            if (CPT == 8) {
                float4 o1; float* o1f = reinterpret_cast<float*>(&o1);
#pragma unroll
                for (int j = 0; j < 4; ++j) {
                    float v = acc[i][4 + j] * scB[j] + biB[j];
                    if (DO_GELU) v = gelu_f(v);
                    if (DO_RES) v += resid[(size_t)r * M + 64 + 4 * colgrp + j];
                    o1f[j] = v;
                }
                *reinterpret_cast<float4*>(Y + (size_t)r * M + 64 + 4 * colgrp) = o1;
            }
        }
    }
}

// ---------------------------------------------------------------------------
// CSR build + degree
// ---------------------------------------------------------------------------
__global__ void count_kernel(const int* __restrict__ dst, int* __restrict__ cnt, int E)
{
    int e = blockIdx.x * 256 + threadIdx.x;
    if (e < E) atomicAdd(&cnt[dst[e]], 1);
}

__global__ void dinv_kernel(const int* __restrict__ cnt, float* __restrict__ dinv, int n)
{
    int i = blockIdx.x * 256 + threadIdx.x;
    if (i < n) dinv[i] = 1.0f / sqrtf((float)cnt[i] + 1.0f);
}

// 3-phase parallel scan: local inclusive per 1024-block, scan block sums, add.
__global__ void scan_local(const int* __restrict__ cnt, int* __restrict__ rowptr,
                           int* __restrict__ bsum, int n)
{
    __shared__ int sd[1024];
    const int tid = threadIdx.x;
    const int i = blockIdx.x * 1024 + tid;
    int v = (i < n) ? cnt[i] : 0;
    sd[tid] = v;
    __syncthreads();
    for (int off = 1; off < 1024; off <<= 1) {
        int t = (tid >= off) ? sd[tid - off] : 0;
        __syncthreads();
        sd[tid] += t;
        __syncthreads();
    }
    if (i < n) rowptr[i + 1] = sd[tid];
    if (tid == 1023) bsum[blockIdx.x] = sd[1023];
}

__global__ void scan_bsum(int* __restrict__ bsum, int nb)
{
    const int lane = threadIdx.x;  // 64 threads, nb <= 64
    int orig = (lane < nb) ? bsum[lane] : 0;
    int v = orig;
#pragma unroll
    for (int off = 1; off < 64; off <<= 1) {
        int t = __shfl_up(v, off);
        if (lane >= off) v += t;
    }
    if (lane < nb) bsum[lane] = v - orig;  // exclusive prefix
}

__global__ void scan_add(int* __restrict__ rowptr, const int* __restrict__ bsum, int n)
{
    const int i = blockIdx.x * 1024 + threadIdx.x;
    if (i < n) rowptr[i + 1] += bsum[blockIdx.x];
    if (i == 0) rowptr[0] = 0;
}

__global__ void fill_kernel(const int* __restrict__ src, const int* __restrict__ dst,
                            const float* __restrict__ dinv, const int* __restrict__ rowptr,
                            int* __restrict__ cursor, int* __restrict__ csr_src,
                            float* __restrict__ csr_w, int E)
{
    int e = blockIdx.x * 256 + threadIdx.x;
    if (e < E) {
        const int d = dst[e], s = src[e];
        const int pos = rowptr[d] + atomicAdd(&cursor[d], 1);
        csr_src[pos] = s;
        csr_w[pos] = dinv[s] * dinv[d];
    }
}

// ---------------------------------------------------------------------------
// Aggregation (gather over CSR): ah[n] = h[n]*snorm + sum_e h[src_e]*w_e
// 32 threads/node (float4 lanes), 8 nodes/block, 4-edge unroll for ILP.
// ---------------------------------------------------------------------------
#define FMA4(A, Wt, V) { A.x = fmaf(Wt, V.x, A.x); A.y = fmaf(Wt, V.y, A.y); \
                         A.z = fmaf(Wt, V.z, A.z); A.w = fmaf(Wt, V.w, A.w); }

__global__ __launch_bounds__(256)
void agg_kernel(const float* __restrict__ h, const int* __restrict__ csr_src,
                const float* __restrict__ csr_w, const int* __restrict__ rowptr,
                const float* __restrict__ dinv, float* __restrict__ ah, int n)
{
    const int node = blockIdx.x * 8 + (threadIdx.x >> 5);
    if (node >= n) return;
    const int lane = threadIdx.x & 31;  // float4 index within the 128-wide row
    const float4* __restrict__ h4 = reinterpret_cast<const float4*>(h);

    const float di = dinv[node];
    const float sw = di * di;
    const float4 self = h4[(size_t)node * 32 + lane];
    float4 a0, a1;
    a0.x = self.x * sw; a0.y = self.y * sw; a0.z = self.z * sw; a0.w = self.w * sw;
    a1.x = 0.f; a1.y = 0.f; a1.z = 0.f; a1.w = 0.f;

    const int beg = rowptr[node], end = rowptr[node + 1];
    int s = beg;
    for (; s + 4 <= end; s += 4) {
        const int n0 = csr_src[s+0], n1 = csr_src[s+1], n2 = csr_src[s+2], n3 = csr_src[s+3];
        const float w0 = csr_w[s+0], w1 = csr_w[s+1], w2 = csr_w[s+2], w3 = csr_w[s+3];
        const float4 v0 = h4[(size_t)n0 * 32 + lane];
        const float4 v1 = h4[(size_t)n1 * 32 + lane];
        const float4 v2 = h4[(size_t)n2 * 32 + lane];
        const float4 v3 = h4[(size_t)n3 * 32 + lane];
        FMA4(a0, w0, v0); FMA4(a1, w1, v1); FMA4(a0, w2, v2); FMA4(a1, w3, v3);
    }
    for (; s < end; ++s) {
        const int sn = csr_src[s];
        const float w = csr_w[s];
        const float4 v = h4[(size_t)sn * 32 + lane];
        FMA4(a0, w, v);
    }
    float4 o;
    o.x = a0.x + a1.x; o.y = a0.y + a1.y; o.z = a0.z + a1.z; o.w = a0.w + a1.w;
    reinterpret_cast<float4*>(ah)[(size_t)node * 32 + lane] = o;
}

// ---------------------------------------------------------------------------
// batch is sorted: per-graph boundaries via binary search
// ---------------------------------------------------------------------------
__global__ void bounds_kernel(const int* __restrict__ batch, int* __restrict__ bound, int n, int g)
{
    const int t = blockIdx.x * blockDim.x + threadIdx.x;
    if (t > g) return;
    int lo = 0, hi = n;
    while (lo < hi) { int mid = (lo + hi) >> 1; if (batch[mid] < t) lo = mid + 1; else hi = mid; }
    bound[t] = lo;
}

// ---------------------------------------------------------------------------
// 2-stage deterministic pooling. Stage 1: 16 fixed chunks per graph.
// ---------------------------------------------------------------------------
__global__ void pool_partial(const float* __restrict__ h, const float* __restrict__ aw,
                             const int* __restrict__ bound, float* __restrict__ ps,
                             float* __restrict__ pm, float* __restrict__ pw)
{
    const int g = blockIdx.x >> 4;
    const int c = blockIdx.x & (POOL_NC - 1);
    const int f = threadIdx.x;  // 128 threads
    const int beg = bound[g], end = bound[g + 1];
    const int len = end - beg;
    const int cbeg = beg + (int)(((long long)len * c) / POOL_NC);
    const int cend = beg + (int)(((long long)len * (c + 1)) / POOL_NC);
    float s = 0.f, m = -FLT_MAX, w = 0.f;
    for (int node = cbeg; node < cend; ++node) {
        const float v = h[(size_t)node * 128 + f];
        const float a = aw[node];
        s += v;
        m = fmaxf(m, v);
        w = fmaf(v, a, w);
    }
    const size_t idx = ((size_t)g * POOL_NC + c) * 128 + f;
    ps[idx] = s; pm[idx] = m; pw[idx] = w;
}

__global__ void pool_final(const float* __restrict__ ps, const float* __restrict__ pm,
                           const float* __restrict__ pw, const int* __restrict__ bound,
                           float* __restrict__ comb)
{
    const int g = blockIdx.x;
    const int f = threadIdx.x;  // 128 threads
    float s = 0.f, m = -FLT_MAX, w = 0.f;
#pragma unroll
    for (int c = 0; c < POOL_NC; ++c) {
        const size_t idx = ((size_t)g * POOL_NC + c) * 128 + f;
        s += ps[idx];
        m = fmaxf(m, pm[idx]);
        w += pw[idx];
    }
    float cn = (float)(bound[g + 1] - bound[g]);
    if (cn < 1.f) cn = 1.f;
    comb[(size_t)g * 512 + f]       = s / cn;
    comb[(size_t)g * 512 + 128 + f] = m;
    comb[(size_t)g * 512 + 256 + f] = s / cn;
    comb[(size_t)g * 512 + 384 + f] = w / cn;
}

// ---------------------------------------------------------------------------
// small row-GEMM for the classifier head (G=128 rows): one block per row
// ---------------------------------------------------------------------------
template<bool DO_BN, bool DO_GELU>
__global__ void rowgemm(const float* __restrict__ X, const float* __restrict__ W,
                        const float* __restrict__ bias, const float* __restrict__ gam,
                        const float* __restrict__ beta, float* __restrict__ Y,
                        int K, int M)
{
    __shared__ float xs[512];
    const int row = blockIdx.x;
    for (int i = threadIdx.x; i < K; i += blockDim.x) xs[i] = X[(size_t)row * K + i];
    __syncthreads();
    const int c = threadIdx.x;
    if (c < M) {
        float acc = 0.f;
        for (int k = 0; k < K; ++k) acc = fmaf(xs[k], W[(size_t)k * M + c], acc);
        float v;
        if (DO_BN) { const float g = gam[c]; const float sc = g * BNS_F; v = acc * sc + (bias[c] * sc + beta[c]); }
        else       { v = acc + bias[c]; }
        if (DO_GELU) v = gelu_f(v);
        Y[(size_t)row * M + c] = v;
    }
}

// ---------------------------------------------------------------------------
extern "C" void kernel_launch(void* const* d_in, const int* in_sizes, int n_in,
                              void* d_out, int out_size, void* d_ws, size_t ws_size,
                              hipStream_t stream)
{
    const float* x     = (const float*)d_in[0];
    const int*   ei    = (const int*)d_in[1];
    const int*   batch = (const int*)d_in[2];
    const float* W1  = (const float*)d_in[3];
    const float* b1  = (const float*)d_in[4];
    const float* g1  = (const float*)d_in[5];
    const float* be1 = (const float*)d_in[6];
    const float* W2  = (const float*)d_in[7];
    const float* b2  = (const float*)d_in[8];
    const float* g2  = (const float*)d_in[9];
    const float* be2 = (const float*)d_in[10];
    const float* Wg  = (const float*)d_in[11];
    const float* bg  = (const float*)d_in[12];
    const float* gg  = (const float*)d_in[13];
    const float* bgg = (const float*)d_in[14];
    const float* Wa1 = (const float*)d_in[15];
    const float* ba1 = (const float*)d_in[16];
    const float* Wa2 = (const float*)d_in[17];
    const float* ba2 = (const float*)d_in[18];
    const float* Wc1 = (const float*)d_in[19];
    const float* bc1 = (const float*)d_in[20];
    const float* gc1 = (const float*)d_in[21];
    const float* bec1= (const float*)d_in[22];
    const float* Wc2 = (const float*)d_in[23];
    const float* bc2 = (const float*)d_in[24];
    const float* gc2 = (const float*)d_in[25];
    const float* bec2= (const float*)d_in[26];
    const float* Wc3 = (const float*)d_in[27];
    const float* bc3 = (const float*)d_in[28];
    const float* gc3 = (const float*)d_in[29];
    const float* bec3= (const float*)d_in[30];
    const float* Wc4 = (const float*)d_in[31];
    const float* bc4 = (const float*)d_in[32];
    float* out = (float*)d_out;

    const int N = in_sizes[0] / 128;
    const int E = in_sizes[1] / 2;
    const int G = GGRAPHS;

    // workspace carve-up
    size_t off = 0;
    auto alloc = [&](size_t bytes) -> void* {
        void* p = (char*)d_ws + off;
        off += (bytes + 255) & ~(size_t)255;
        return p;
    };
    float* hA     = (float*)alloc((size_t)N * 128 * 4);
    float* hB     = (float*)alloc((size_t)N * 128 * 4);
    float* aw     = (float*)alloc((size_t)N * 4);
    float* dinv   = (float*)alloc((size_t)N * 4);
    int*   cnt    = (int*)alloc((size_t)N * 4);
    int*   cursor = (int*)alloc((size_t)N * 4);
    int*   rowptr = (int*)alloc((size_t)(N + 1) * 4);
    int*   bsum   = (int*)alloc(64 * 4);
    int*   csr_src= (int*)alloc((size_t)E * 4);
    float* csr_w  = (float*)alloc((size_t)E * 4);
    int*   bound  = (int*)alloc((size_t)(G + 1) * 4);
    float* comb   = (float*)alloc((size_t)G * 512 * 4);
    float* ps     = (float*)alloc((size_t)G * POOL_NC * 128 * 4);
    float* pm     = (float*)alloc((size_t)G * POOL_NC * 128 * 4);
    float* pw     = (float*)alloc((size_t)G * POOL_NC * 128 * 4);
    float* z1     = (float*)alloc((size_t)G * 256 * 4);
    float* z2     = (float*)alloc((size_t)G * 128 * 4);
    float* z3     = (float*)alloc((size_t)G * 64 * 4);
    (void)ws_size;

    const int* e_src = ei;
    const int* e_dst = ei + E;

    // ---- CSR build over dst (reused by all 3 GCN layers) ----
    hipMemsetAsync(cnt, 0, (size_t)N * 4, stream);
    hipMemsetAsync(cursor, 0, (size_t)N * 4, stream);
    count_kernel<<<(E + 255) / 256, 256, 0, stream>>>(e_dst, cnt, E);
    dinv_kernel<<<(N + 255) / 256, 256, 0, stream>>>(cnt, dinv, N);
    const int nb = (N + 1023) / 1024;
    scan_local<<<nb, 1024, 0, stream>>>(cnt, rowptr, bsum, N);
    scan_bsum<<<1, 64, 0, stream>>>(bsum, nb);
    scan_add<<<nb, 1024, 0, stream>>>(rowptr, bsum, N);
    fill_kernel<<<(E + 255) / 256, 256, 0, stream>>>(e_src, e_dst, dinv, rowptr, cursor,
                                                     csr_src, csr_w, E);

    const int gblocks = (N + 63) / 64;

    // ---- input projection ----
    gemm_fused<128, true, true, false, false><<<gblocks, 256, 0, stream>>>(
        x,  W1, b1, g1, be1, nullptr, hA, nullptr, nullptr, nullptr, N);
    gemm_fused<128, true, true, false, false><<<gblocks, 256, 0, stream>>>(
        hA, W2, b2, g2, be2, nullptr, hA, nullptr, nullptr, nullptr, N);

    // ---- GCN layers: aggregate-then-transform (linearity) ----
    for (int l = 0; l < 3; ++l) {
        agg_kernel<<<(N + 7) / 8, 256, 0, stream>>>(hA, csr_src, csr_w, rowptr, dinv, hB, N);
        gemm_fused<128, true, true, true, false><<<gblocks, 256, 0, stream>>>(
            hB, Wg + (size_t)l * 128 * 128, bg + (size_t)l * 128,
            gg + (size_t)l * 128, bgg + (size_t)l * 128, hA, hA, nullptr, nullptr, nullptr, N);
    }

    // ---- attention weights (fused: gelu(h@Wa1+ba1)@Wa2+ba2 -> tanh) ----
    gemm_fused<64, false, true, false, true><<<gblocks, 256, 0, stream>>>(
        hA, Wa1, ba1, nullptr, nullptr, nullptr, nullptr, Wa2, ba2, aw, N);

    // ---- pooling ----
    bounds_kernel<<<1, 256, 0, stream>>>(batch, bound, N, G);
    pool_partial<<<G * POOL_NC, 128, 0, stream>>>(hA, aw, bound, ps, pm, pw);
    pool_final<<<G, 128, 0, stream>>>(ps, pm, pw, bound, comb);

    // ---- classifier head ----
    rowgemm<true, true><<<G, 256, 0, stream>>>(comb, Wc1, bc1, gc1, bec1, z1, 512, 256);
    rowgemm<true, true><<<G, 128, 0, stream>>>(z1, Wc2, bc2, gc2, bec2, z2, 256, 128);
    rowgemm<true, true><<<G, 64, 0, stream>>>(z2, Wc3, bc3, gc3, bec3, z3, 128, 64);
    rowgemm<false, false><<<G, 64, 0, stream>>>(z3, Wc4, bc4, nullptr, nullptr, out, 64, 4);
}

// Round 3
// 582.903 us; speedup vs baseline: 1.7432x; 1.1035x over previous
//
#include <hip/hip_runtime.h>
#include <hip/hip_bf16.h>
#include <float.h>

// ---------------------------------------------------------------------------
// ImprovedTransformerGNN: fp32 end-to-end.
// N=50000, E=600000, H=128, IN=128, C=4, L=3, G=128.
// R3: classifier head rewritten (rowgemm2: K-split across block + unroll-4 ILP,
//     grid G*(M/64); final layer = wave shuffle-reduce). Rest unchanged.
// ---------------------------------------------------------------------------

#define GGRAPHS 128
#define POOL_NC 16

__device__ __forceinline__ float gelu_f(float x) {
    return 0.5f * x * (1.0f + erff(x * 0.7071067811865476f));
}

static constexpr float BNS_F = 0.99999500003749968f;  // 1/sqrt(1+1e-5)

// ---------------------------------------------------------------------------
// Fused GEMM: Y[nrows,M] = act( (X[nrows,128] @ W[128,M]) * colscale + colbias ) (+ resid)
// Block: 256 threads, 64 rows. Thread (rowgrp=tid>>4, colgrp=tid&15) computes
// 4 rows x CPT cols. In-place X==Y safe (wave reads only its own rows; writes
// after the k-loop). DO_AW: skip Y store, emit aw[r]=tanh(gelu(row)@Wa2+ba2).
// ---------------------------------------------------------------------------
template<int M, bool DO_BN, bool DO_GELU, bool DO_RES, bool DO_AW>
__global__ __launch_bounds__(256, 4)
void gemm_fused(const float* __restrict__ X, const float* __restrict__ W,
                const float* __restrict__ bias, const float* __restrict__ gam,
                const float* __restrict__ beta, const float* __restrict__ resid,
                float* __restrict__ Y, const float* __restrict__ Wa2,
                const float* __restrict__ ba2, float* __restrict__ awout, int nrows)
{
    constexpr int CPT = M / 16;   // 8 (M=128) or 4 (M=64)
    constexpr int NF4 = M / 4;    // float4 per k-row
    __shared__ float4 Ws[128 * NF4];

    const int tid = threadIdx.x;
    const float4* W4 = reinterpret_cast<const float4*>(W);
#pragma unroll
    for (int i = 0; i < (128 * NF4) / 256; ++i)
        Ws[tid + i * 256] = W4[tid + i * 256];
    __syncthreads();

    const int colgrp = tid & 15;
    const int rowgrp = tid >> 4;
    const int r0 = blockIdx.x * 64 + rowgrp * 4;

    float acc[4][CPT];
#pragma unroll
    for (int i = 0; i < 4; ++i)
#pragma unroll
        for (int j = 0; j < CPT; ++j) acc[i][j] = 0.f;

    const float4* xp[4];
#pragma unroll
    for (int i = 0; i < 4; ++i) {
        int r = r0 + i; if (r >= nrows) r = nrows - 1;
        xp[i] = reinterpret_cast<const float4*>(X + (size_t)r * 128);
    }
    float4 xv[4];
#pragma unroll
    for (int i = 0; i < 4; ++i) xv[i] = xp[i][0];

    for (int k4 = 0; k4 < 32; ++k4) {
        float4 xn[4];
#pragma unroll
        for (int i = 0; i < 4; ++i) xn[i] = xv[i];
        if (k4 < 31) {
#pragma unroll
            for (int i = 0; i < 4; ++i) xn[i] = xp[i][k4 + 1];
        }
#pragma unroll
        for (int kk = 0; kk < 4; ++kk) {
            const int k = k4 * 4 + kk;
            const float4 w0 = Ws[k * NF4 + colgrp];
            float4 w1;
            if (CPT == 8) w1 = Ws[k * NF4 + 16 + colgrp];
#pragma unroll
            for (int i = 0; i < 4; ++i) {
                const float xs = reinterpret_cast<const float*>(&xv[i])[kk];
                acc[i][0] = fmaf(xs, w0.x, acc[i][0]);
                acc[i][1] = fmaf(xs, w0.y, acc[i][1]);
                acc[i][2] = fmaf(xs, w0.z, acc[i][2]);
                acc[i][3] = fmaf(xs, w0.w, acc[i][3]);
                if (CPT == 8) {
                    acc[i][4] = fmaf(xs, w1.x, acc[i][4]);
                    acc[i][5] = fmaf(xs, w1.y, acc[i][5]);
                    acc[i][6] = fmaf(xs, w1.z, acc[i][6]);
                    acc[i][7] = fmaf(xs, w1.w, acc[i][7]);
                }
            }
        }
#pragma unroll
        for (int i = 0; i < 4; ++i) xv[i] = xn[i];
    }

    // epilogue: per-column scale/bias (BN folded), gelu, residual / aw
    float scA[4], biA[4], scB[4], biB[4];
#pragma unroll
    for (int j = 0; j < 4; ++j) {
        const int c = 4 * colgrp + j;
        if (DO_BN) { float g = gam[c]; scA[j] = g * BNS_F; biA[j] = bias[c] * scA[j] + beta[c]; }
        else       { scA[j] = 1.f;     biA[j] = bias[c]; }
        if (CPT == 8) {
            const int c2 = 64 + 4 * colgrp + j;
            if (DO_BN) { float g = gam[c2]; scB[j] = g * BNS_F; biB[j] = bias[c2] * scB[j] + beta[c2]; }
            else       { scB[j] = 1.f;      biB[j] = bias[c2]; }
        }
    }

    if (DO_AW) {
        float wa[4];
#pragma unroll
        for (int j = 0; j < 4; ++j) wa[j] = Wa2[4 * colgrp + j];
        const float ba2v = ba2[0];
#pragma unroll
        for (int i = 0; i < 4; ++i) {
            float p = 0.f;
#pragma unroll
            for (int j = 0; j < 4; ++j) {
                float v = acc[i][j] * scA[j] + biA[j];
                if (DO_GELU) v = gelu_f(v);
                p = fmaf(v, wa[j], p);
            }
            p += __shfl_xor(p, 1);
            p += __shfl_xor(p, 2);
            p += __shfl_xor(p, 4);
            p += __shfl_xor(p, 8);
            const int r = r0 + i;
            if (colgrp == 0 && r < nrows) awout[r] = tanhf(p + ba2v);
        }
        return;
    }

#pragma unroll
    for (int i = 0; i < 4; ++i) {
        const int r = r0 + i;
        if (r < nrows) {
            float4 o0; float* o0f = reinterpret_cast<float*>(&o0);
#pragma unroll
            for (int j = 0; j < 4; ++j) {
                float v = acc[i][j] * scA[j] + biA[j];
                if (DO_GELU) v = gelu_f(v);
                if (DO_RES) v += resid[(size_t)r * M + 4 * colgrp + j];
                o0f[j] = v;
            }
            *reinterpret_cast<float4*>(Y + (size_t)r * M + 4 * colgrp) = o0;
            if (CPT == 8) {
                float4 o1; float* o1f = reinterpret_cast<float*>(&o1);
#pragma unroll
                for (int j = 0; j < 4; ++j) {
                    float v = acc[i][4 + j] * scB[j] + biB[j];
                    if (DO_GELU) v = gelu_f(v);
                    if (DO_RES) v += resid[(size_t)r * M + 64 + 4 * colgrp + j];
                    o1f[j] = v;
                }
                *reinterpret_cast<float4*>(Y + (size_t)r * M + 64 + 4 * colgrp) = o1;
            }
        }
    }
}

// ---------------------------------------------------------------------------
// CSR build + degree
// ---------------------------------------------------------------------------
__global__ void count_kernel(const int* __restrict__ dst, int* __restrict__ cnt, int E)
{
    int e = blockIdx.x * 256 + threadIdx.x;
    if (e < E) atomicAdd(&cnt[dst[e]], 1);
}

__global__ void dinv_kernel(const int* __restrict__ cnt, float* __restrict__ dinv, int n)
{
    int i = blockIdx.x * 256 + threadIdx.x;
    if (i < n) dinv[i] = 1.0f / sqrtf((float)cnt[i] + 1.0f);
}

// 3-phase parallel scan
__global__ void scan_local(const int* __restrict__ cnt, int* __restrict__ rowptr,
                           int* __restrict__ bsum, int n)
{
    __shared__ int sd[1024];
    const int tid = threadIdx.x;
    const int i = blockIdx.x * 1024 + tid;
    int v = (i < n) ? cnt[i] : 0;
    sd[tid] = v;
    __syncthreads();
    for (int off = 1; off < 1024; off <<= 1) {
        int t = (tid >= off) ? sd[tid - off] : 0;
        __syncthreads();
        sd[tid] += t;
        __syncthreads();
    }
    if (i < n) rowptr[i + 1] = sd[tid];
    if (tid == 1023) bsum[blockIdx.x] = sd[1023];
}

__global__ void scan_bsum(int* __restrict__ bsum, int nb)
{
    const int lane = threadIdx.x;  // 64 threads, nb <= 64
    int orig = (lane < nb) ? bsum[lane] : 0;
    int v = orig;
#pragma unroll
    for (int off = 1; off < 64; off <<= 1) {
        int t = __shfl_up(v, off);
        if (lane >= off) v += t;
    }
    if (lane < nb) bsum[lane] = v - orig;  // exclusive prefix
}

__global__ void scan_add(int* __restrict__ rowptr, const int* __restrict__ bsum, int n)
{
    const int i = blockIdx.x * 1024 + threadIdx.x;
    if (i < n) rowptr[i + 1] += bsum[blockIdx.x];
    if (i == 0) rowptr[0] = 0;
}

__global__ void fill_kernel(const int* __restrict__ src, const int* __restrict__ dst,
                            const float* __restrict__ dinv, const int* __restrict__ rowptr,
                            int* __restrict__ cursor, int* __restrict__ csr_src,
                            float* __restrict__ csr_w, int E)
{
    int e = blockIdx.x * 256 + threadIdx.x;
    if (e < E) {
        const int d = dst[e], s = src[e];
        const int pos = rowptr[d] + atomicAdd(&cursor[d], 1);
        csr_src[pos] = s;
        csr_w[pos] = dinv[s] * dinv[d];
    }
}

// ---------------------------------------------------------------------------
// Aggregation (gather over CSR): ah[n] = h[n]*snorm + sum_e h[src_e]*w_e
// 32 threads/node (float4 lanes), 8 nodes/block, 4-edge unroll for ILP.
// ---------------------------------------------------------------------------
#define FMA4(A, Wt, V) { A.x = fmaf(Wt, V.x, A.x); A.y = fmaf(Wt, V.y, A.y); \
                         A.z = fmaf(Wt, V.z, A.z); A.w = fmaf(Wt, V.w, A.w); }

__global__ __launch_bounds__(256)
void agg_kernel(const float* __restrict__ h, const int* __restrict__ csr_src,
                const float* __restrict__ csr_w, const int* __restrict__ rowptr,
                const float* __restrict__ dinv, float* __restrict__ ah, int n)
{
    const int node = blockIdx.x * 8 + (threadIdx.x >> 5);
    if (node >= n) return;
    const int lane = threadIdx.x & 31;  // float4 index within the 128-wide row
    const float4* __restrict__ h4 = reinterpret_cast<const float4*>(h);

    const float di = dinv[node];
    const float sw = di * di;
    const float4 self = h4[(size_t)node * 32 + lane];
    float4 a0, a1;
    a0.x = self.x * sw; a0.y = self.y * sw; a0.z = self.z * sw; a0.w = self.w * sw;
    a1.x = 0.f; a1.y = 0.f; a1.z = 0.f; a1.w = 0.f;

    const int beg = rowptr[node], end = rowptr[node + 1];
    int s = beg;
    for (; s + 4 <= end; s += 4) {
        const int n0 = csr_src[s+0], n1 = csr_src[s+1], n2 = csr_src[s+2], n3 = csr_src[s+3];
        const float w0 = csr_w[s+0], w1 = csr_w[s+1], w2 = csr_w[s+2], w3 = csr_w[s+3];
        const float4 v0 = h4[(size_t)n0 * 32 + lane];
        const float4 v1 = h4[(size_t)n1 * 32 + lane];
        const float4 v2 = h4[(size_t)n2 * 32 + lane];
        const float4 v3 = h4[(size_t)n3 * 32 + lane];
        FMA4(a0, w0, v0); FMA4(a1, w1, v1); FMA4(a0, w2, v2); FMA4(a1, w3, v3);
    }
    for (; s < end; ++s) {
        const int sn = csr_src[s];
        const float w = csr_w[s];
        const float4 v = h4[(size_t)sn * 32 + lane];
        FMA4(a0, w, v);
    }
    float4 o;
    o.x = a0.x + a1.x; o.y = a0.y + a1.y; o.z = a0.z + a1.z; o.w = a0.w + a1.w;
    reinterpret_cast<float4*>(ah)[(size_t)node * 32 + lane] = o;
}

// ---------------------------------------------------------------------------
// batch is sorted: per-graph boundaries via binary search
// ---------------------------------------------------------------------------
__global__ void bounds_kernel(const int* __restrict__ batch, int* __restrict__ bound, int n, int g)
{
    const int t = blockIdx.x * blockDim.x + threadIdx.x;
    if (t > g) return;
    int lo = 0, hi = n;
    while (lo < hi) { int mid = (lo + hi) >> 1; if (batch[mid] < t) lo = mid + 1; else hi = mid; }
    bound[t] = lo;
}

// ---------------------------------------------------------------------------
// 2-stage deterministic pooling. Stage 1: 16 fixed chunks per graph.
// ---------------------------------------------------------------------------
__global__ void pool_partial(const float* __restrict__ h, const float* __restrict__ aw,
                             const int* __restrict__ bound, float* __restrict__ ps,
                             float* __restrict__ pm, float* __restrict__ pw)
{
    const int g = blockIdx.x >> 4;
    const int c = blockIdx.x & (POOL_NC - 1);
    const int f = threadIdx.x;  // 128 threads
    const int beg = bound[g], end = bound[g + 1];
    const int len = end - beg;
    const int cbeg = beg + (int)(((long long)len * c) / POOL_NC);
    const int cend = beg + (int)(((long long)len * (c + 1)) / POOL_NC);
    float s = 0.f, m = -FLT_MAX, w = 0.f;
    for (int node = cbeg; node < cend; ++node) {
        const float v = h[(size_t)node * 128 + f];
        const float a = aw[node];
        s += v;
        m = fmaxf(m, v);
        w = fmaf(v, a, w);
    }
    const size_t idx = ((size_t)g * POOL_NC + c) * 128 + f;
    ps[idx] = s; pm[idx] = m; pw[idx] = w;
}

__global__ void pool_final(const float* __restrict__ ps, const float* __restrict__ pm,
                           const float* __restrict__ pw, const int* __restrict__ bound,
                           float* __restrict__ comb)
{
    const int g = blockIdx.x;
    const int f = threadIdx.x;  // 128 threads
    float s = 0.f, m = -FLT_MAX, w = 0.f;
#pragma unroll
    for (int c = 0; c < POOL_NC; ++c) {
        const size_t idx = ((size_t)g * POOL_NC + c) * 128 + f;
        s += ps[idx];
        m = fmaxf(m, pm[idx]);
        w += pw[idx];
    }
    float cn = (float)(bound[g + 1] - bound[g]);
    if (cn < 1.f) cn = 1.f;
    comb[(size_t)g * 512 + f]       = s / cn;
    comb[(size_t)g * 512 + 128 + f] = m;
    comb[(size_t)g * 512 + 256 + f] = s / cn;
    comb[(size_t)g * 512 + 384 + f] = w / cn;
}

// ---------------------------------------------------------------------------
// classifier head GEMM, parallel version: grid = G * (M/64); block 256 =
// 64 cols x 4 k-quarters. Compile-time K/M -> unrolled ILP; LDS combine.
// ---------------------------------------------------------------------------
template<int K, int M, bool DO_BN, bool DO_GELU>
__global__ __launch_bounds__(256)
void rowgemm2(const float* __restrict__ X, const float* __restrict__ W,
              const float* __restrict__ bias, const float* __restrict__ gam,
              const float* __restrict__ beta, float* __restrict__ Y)
{
    constexpr int NC = M / 64;
    constexpr int KQ = K / 4;
    const int row = blockIdx.x / NC;
    const int lane = threadIdx.x & 63;
    const int c = (blockIdx.x % NC) * 64 + lane;
    const int q = threadIdx.x >> 6;  // k-quarter 0..3

    const float* __restrict__ xq = X + (size_t)row * K + q * KQ;
    const float* __restrict__ wq = W + (size_t)(q * KQ) * M + c;

    float a0 = 0.f, a1 = 0.f, a2 = 0.f, a3 = 0.f;
#pragma unroll 4
    for (int k = 0; k < KQ; k += 4) {
        const float4 xv = *reinterpret_cast<const float4*>(xq + k);
        a0 = fmaf(xv.x, wq[(size_t)(k + 0) * M], a0);
        a1 = fmaf(xv.y, wq[(size_t)(k + 1) * M], a1);
        a2 = fmaf(xv.z, wq[(size_t)(k + 2) * M], a2);
        a3 = fmaf(xv.w, wq[(size_t)(k + 3) * M], a3);
    }
    __shared__ float part[4][64];
    part[q][lane] = (a0 + a1) + (a2 + a3);
    __syncthreads();
    if (q == 0) {
        float v = (part[0][lane] + part[1][lane]) + (part[2][lane] + part[3][lane]);
        if (DO_BN) { const float g = gam[c]; const float sc = g * BNS_F; v = v * sc + (bias[c] * sc + beta[c]); }
        else       { v = v + bias[c]; }
        if (DO_GELU) v = gelu_f(v);
        Y[(size_t)row * M + c] = v;
    }
}

// final layer: [G,64] @ [64,4] + bias; one wave per row, shuffle reduce
__global__ void rowgemm_final(const float* __restrict__ X, const float* __restrict__ W,
                              const float* __restrict__ bias, float* __restrict__ Y)
{
    const int row = blockIdx.x;
    const int lane = threadIdx.x;  // 64
    const float xv = X[(size_t)row * 64 + lane];
    const float4 wr = *reinterpret_cast<const float4*>(W + lane * 4);
    float a0 = xv * wr.x, a1 = xv * wr.y, a2 = xv * wr.z, a3 = xv * wr.w;
#pragma unroll
    for (int off = 32; off; off >>= 1) {
        a0 += __shfl_xor(a0, off);
        a1 += __shfl_xor(a1, off);
        a2 += __shfl_xor(a2, off);
        a3 += __shfl_xor(a3, off);
    }
    if (lane == 0) {
        Y[(size_t)row * 4 + 0] = a0 + bias[0];
        Y[(size_t)row * 4 + 1] = a1 + bias[1];
        Y[(size_t)row * 4 + 2] = a2 + bias[2];
        Y[(size_t)row * 4 + 3] = a3 + bias[3];
    }
}

// ---------------------------------------------------------------------------
extern "C" void kernel_launch(void* const* d_in, const int* in_sizes, int n_in,
                              void* d_out, int out_size, void* d_ws, size_t ws_size,
                              hipStream_t stream)
{
    const float* x     = (const float*)d_in[0];
    const int*   ei    = (const int*)d_in[1];
    const int*   batch = (const int*)d_in[2];
    const float* W1  = (const float*)d_in[3];
    const float* b1  = (const float*)d_in[4];
    const float* g1  = (const float*)d_in[5];
    const float* be1 = (const float*)d_in[6];
    const float* W2  = (const float*)d_in[7];
    const float* b2  = (const float*)d_in[8];
    const float* g2  = (const float*)d_in[9];
    const float* be2 = (const float*)d_in[10];
    const float* Wg  = (const float*)d_in[11];
    const float* bg  = (const float*)d_in[12];
    const float* gg  = (const float*)d_in[13];
    const float* bgg = (const float*)d_in[14];
    const float* Wa1 = (const float*)d_in[15];
    const float* ba1 = (const float*)d_in[16];
    const float* Wa2 = (const float*)d_in[17];
    const float* ba2 = (const float*)d_in[18];
    const float* Wc1 = (const float*)d_in[19];
    const float* bc1 = (const float*)d_in[20];
    const float* gc1 = (const float*)d_in[21];
    const float* bec1= (const float*)d_in[22];
    const float* Wc2 = (const float*)d_in[23];
    const float* bc2 = (const float*)d_in[24];
    const float* gc2 = (const float*)d_in[25];
    const float* bec2= (const float*)d_in[26];
    const float* Wc3 = (const float*)d_in[27];
    const float* bc3 = (const float*)d_in[28];
    const float* gc3 = (const float*)d_in[29];
    const float* bec3= (const float*)d_in[30];
    const float* Wc4 = (const float*)d_in[31];
    const float* bc4 = (const float*)d_in[32];
    float* out = (float*)d_out;

    const int N = in_sizes[0] / 128;
    const int E = in_sizes[1] / 2;
    const int G = GGRAPHS;

    // workspace carve-up
    size_t off = 0;
    auto alloc = [&](size_t bytes) -> void* {
        void* p = (char*)d_ws + off;
        off += (bytes + 255) & ~(size_t)255;
        return p;
    };
    float* hA     = (float*)alloc((size_t)N * 128 * 4);
    float* hB     = (float*)alloc((size_t)N * 128 * 4);
    float* aw     = (float*)alloc((size_t)N * 4);
    float* dinv   = (float*)alloc((size_t)N * 4);
    int*   cnt    = (int*)alloc((size_t)N * 4);
    int*   cursor = (int*)alloc((size_t)N * 4);
    int*   rowptr = (int*)alloc((size_t)(N + 1) * 4);
    int*   bsum   = (int*)alloc(64 * 4);
    int*   csr_src= (int*)alloc((size_t)E * 4);
    float* csr_w  = (float*)alloc((size_t)E * 4);
    int*   bound  = (int*)alloc((size_t)(G + 1) * 4);
    float* comb   = (float*)alloc((size_t)G * 512 * 4);
    float* ps     = (float*)alloc((size_t)G * POOL_NC * 128 * 4);
    float* pm     = (float*)alloc((size_t)G * POOL_NC * 128 * 4);
    float* pw     = (float*)alloc((size_t)G * POOL_NC * 128 * 4);
    float* z1     = (float*)alloc((size_t)G * 256 * 4);
    float* z2     = (float*)alloc((size_t)G * 128 * 4);
    float* z3     = (float*)alloc((size_t)G * 64 * 4);
    (void)ws_size;

    const int* e_src = ei;
    const int* e_dst = ei + E;

    // ---- CSR build over dst (reused by all 3 GCN layers) ----
    hipMemsetAsync(cnt, 0, (size_t)N * 4, stream);
    hipMemsetAsync(cursor, 0, (size_t)N * 4, stream);
    count_kernel<<<(E + 255) / 256, 256, 0, stream>>>(e_dst, cnt, E);
    dinv_kernel<<<(N + 255) / 256, 256, 0, stream>>>(cnt, dinv, N);
    const int nb = (N + 1023) / 1024;
    scan_local<<<nb, 1024, 0, stream>>>(cnt, rowptr, bsum, N);
    scan_bsum<<<1, 64, 0, stream>>>(bsum, nb);
    scan_add<<<nb, 1024, 0, stream>>>(rowptr, bsum, N);
    fill_kernel<<<(E + 255) / 256, 256, 0, stream>>>(e_src, e_dst, dinv, rowptr, cursor,
                                                     csr_src, csr_w, E);

    const int gblocks = (N + 63) / 64;

    // ---- input projection ----
    gemm_fused<128, true, true, false, false><<<gblocks, 256, 0, stream>>>(
        x,  W1, b1, g1, be1, nullptr, hA, nullptr, nullptr, nullptr, N);
    gemm_fused<128, true, true, false, false><<<gblocks, 256, 0, stream>>>(
        hA, W2, b2, g2, be2, nullptr, hA, nullptr, nullptr, nullptr, N);

    // ---- GCN layers: aggregate-then-transform (linearity) ----
    for (int l = 0; l < 3; ++l) {
        agg_kernel<<<(N + 7) / 8, 256, 0, stream>>>(hA, csr_src, csr_w, rowptr, dinv, hB, N);
        gemm_fused<128, true, true, true, false><<<gblocks, 256, 0, stream>>>(
            hB, Wg + (size_t)l * 128 * 128, bg + (size_t)l * 128,
            gg + (size_t)l * 128, bgg + (size_t)l * 128, hA, hA, nullptr, nullptr, nullptr, N);
    }

    // ---- attention weights (fused: gelu(h@Wa1+ba1)@Wa2+ba2 -> tanh) ----
    gemm_fused<64, false, true, false, true><<<gblocks, 256, 0, stream>>>(
        hA, Wa1, ba1, nullptr, nullptr, nullptr, nullptr, Wa2, ba2, aw, N);

    // ---- pooling ----
    bounds_kernel<<<1, 256, 0, stream>>>(batch, bound, N, G);
    pool_partial<<<G * POOL_NC, 128, 0, stream>>>(hA, aw, bound, ps, pm, pw);
    pool_final<<<G, 128, 0, stream>>>(ps, pm, pw, bound, comb);

    // ---- classifier head ----
    rowgemm2<512, 256, true, true><<<G * 4, 256, 0, stream>>>(comb, Wc1, bc1, gc1, bec1, z1);
    rowgemm2<256, 128, true, true><<<G * 2, 256, 0, stream>>>(z1, Wc2, bc2, gc2, bec2, z2);
    rowgemm2<128, 64,  true, true><<<G * 1, 256, 0, stream>>>(z2, Wc3, bc3, gc3, bec3, z3);
    rowgemm_final<<<G, 64, 0, stream>>>(z3, Wc4, bc4, out);
}

// Round 4
// 540.804 us; speedup vs baseline: 1.8789x; 1.0778x over previous
//
#include <hip/hip_runtime.h>
#include <hip/hip_bf16.h>
#include <float.h>

// ---------------------------------------------------------------------------
// ImprovedTransformerGNN: fp32 end-to-end.
// N=50000, E=600000, H=128, IN=128, C=4, L=3, G=128.
// R4: gemm_fused 128 rows/block (8 rows/thread -> FMA:LDS 5.3:1, was LDS-pipe
//     bound at 1.5x); fill atomic-free via rank from count pass + int2 csr;
//     dinv folded into scan_local.
// ---------------------------------------------------------------------------

#define GGRAPHS 128
#define POOL_NC 16

__device__ __forceinline__ float gelu_f(float x) {
    return 0.5f * x * (1.0f + erff(x * 0.7071067811865476f));
}

static constexpr float BNS_F = 0.99999500003749968f;  // 1/sqrt(1+1e-5)

// ---------------------------------------------------------------------------
// Fused GEMM: Y[nrows,M] = act( (X[nrows,128] @ W[128,M]) * sc + bi ) (+resid)
// Block: 256 threads, 128 rows. colgrp=tid&15 (16 x CPT cols), rowgrp=tid>>4
// (16 x 8 rows). Per kk: 2 LDS b128 reads reused across 8 rows -> VALU-bound.
// W tile in LDS: 64KB (M=128) -> 2 blocks/CU. In-place X==Y safe (each row
// read/written by exactly one thread; writes after k-loop).
// DO_AW: skip Y store, emit aw[r]=tanh(gelu(row)@Wa2+ba2).
// ---------------------------------------------------------------------------
template<int M, bool DO_BN, bool DO_GELU, bool DO_RES, bool DO_AW>
__global__ __launch_bounds__(256, 2)
void gemm_fused(const float* __restrict__ X, const float* __restrict__ W,
                const float* __restrict__ bias, const float* __restrict__ gam,
                const float* __restrict__ beta, const float* __restrict__ resid,
                float* __restrict__ Y, const float* __restrict__ Wa2,
                const float* __restrict__ ba2, float* __restrict__ awout, int nrows)
{
    constexpr int CPT = M / 16;   // 8 (M=128) or 4 (M=64)
    constexpr int NF4 = M / 4;    // float4 per k-row
    __shared__ float4 Ws[128 * NF4];   // 64KB / 32KB

    const int tid = threadIdx.x;
    const float4* W4 = reinterpret_cast<const float4*>(W);
#pragma unroll
    for (int i = 0; i < (128 * NF4) / 256; ++i)
        Ws[tid + i * 256] = W4[tid + i * 256];
    __syncthreads();

    const int colgrp = tid & 15;
    const int rowgrp = tid >> 4;
    const int r0 = blockIdx.x * 128 + rowgrp * 8;

    float acc[8][CPT];
#pragma unroll
    for (int i = 0; i < 8; ++i)
#pragma unroll
        for (int j = 0; j < CPT; ++j) acc[i][j] = 0.f;

    const float4* xp[8];
#pragma unroll
    for (int i = 0; i < 8; ++i) {
        int r = r0 + i; if (r >= nrows) r = nrows - 1;
        xp[i] = reinterpret_cast<const float4*>(X + (size_t)r * 128);
    }
    float4 xv[8];
#pragma unroll
    for (int i = 0; i < 8; ++i) xv[i] = xp[i][0];

    for (int k4 = 0; k4 < 32; ++k4) {
        float4 xn[8];
        if (k4 < 31) {
#pragma unroll
            for (int i = 0; i < 8; ++i) xn[i] = xp[i][k4 + 1];
        }
#pragma unroll
        for (int kk = 0; kk < 4; ++kk) {
            const int k = k4 * 4 + kk;
            const float4 w0 = Ws[k * NF4 + colgrp];
            float4 w1;
            if (CPT == 8) w1 = Ws[k * NF4 + 16 + colgrp];
#pragma unroll
            for (int i = 0; i < 8; ++i) {
                const float xs = reinterpret_cast<const float*>(&xv[i])[kk];
                acc[i][0] = fmaf(xs, w0.x, acc[i][0]);
                acc[i][1] = fmaf(xs, w0.y, acc[i][1]);
                acc[i][2] = fmaf(xs, w0.z, acc[i][2]);
                acc[i][3] = fmaf(xs, w0.w, acc[i][3]);
                if (CPT == 8) {
                    acc[i][4] = fmaf(xs, w1.x, acc[i][4]);
                    acc[i][5] = fmaf(xs, w1.y, acc[i][5]);
                    acc[i][6] = fmaf(xs, w1.z, acc[i][6]);
                    acc[i][7] = fmaf(xs, w1.w, acc[i][7]);
                }
            }
        }
        if (k4 < 31) {
#pragma unroll
            for (int i = 0; i < 8; ++i) xv[i] = xn[i];
        }
    }

    // epilogue: per-column scale/bias (BN folded), gelu, residual / aw
    float scA[4], biA[4], scB[4], biB[4];
#pragma unroll
    for (int j = 0; j < 4; ++j) {
        const int c = 4 * colgrp + j;
        if (DO_BN) { float g = gam[c]; scA[j] = g * BNS_F; biA[j] = bias[c] * scA[j] + beta[c]; }
        else       { scA[j] = 1.f;     biA[j] = bias[c]; }
        if (CPT == 8) {
            const int c2 = 64 + 4 * colgrp + j;
            if (DO_BN) { float g = gam[c2]; scB[j] = g * BNS_F; biB[j] = bias[c2] * scB[j] + beta[c2]; }
            else       { scB[j] = 1.f;      biB[j] = bias[c2]; }
        }
    }

    if (DO_AW) {
        float wa[4];
#pragma unroll
        for (int j = 0; j < 4; ++j) wa[j] = Wa2[4 * colgrp + j];
        const float ba2v = ba2[0];
#pragma unroll
        for (int i = 0; i < 8; ++i) {
            float p = 0.f;
#pragma unroll
            for (int j = 0; j < 4; ++j) {
                float v = acc[i][j] * scA[j] + biA[j];
                if (DO_GELU) v = gelu_f(v);
                p = fmaf(v, wa[j], p);
            }
            p += __shfl_xor(p, 1);
            p += __shfl_xor(p, 2);
            p += __shfl_xor(p, 4);
            p += __shfl_xor(p, 8);
            const int r = r0 + i;
            if (colgrp == 0 && r < nrows) awout[r] = tanhf(p + ba2v);
        }
        return;
    }

#pragma unroll
    for (int i = 0; i < 8; ++i) {
        const int r = r0 + i;
        if (r < nrows) {
            float4 o0; float* o0f = reinterpret_cast<float*>(&o0);
#pragma unroll
            for (int j = 0; j < 4; ++j) {
                float v = acc[i][j] * scA[j] + biA[j];
                if (DO_GELU) v = gelu_f(v);
                if (DO_RES) v += resid[(size_t)r * M + 4 * colgrp + j];
                o0f[j] = v;
            }
            *reinterpret_cast<float4*>(Y + (size_t)r * M + 4 * colgrp) = o0;
            if (CPT == 8) {
                float4 o1; float* o1f = reinterpret_cast<float*>(&o1);
#pragma unroll
                for (int j = 0; j < 4; ++j) {
                    float v = acc[i][4 + j] * scB[j] + biB[j];
                    if (DO_GELU) v = gelu_f(v);
                    if (DO_RES) v += resid[(size_t)r * M + 64 + 4 * colgrp + j];
                    o1f[j] = v;
                }
                *reinterpret_cast<float4*>(Y + (size_t)r * M + 64 + 4 * colgrp) = o1;
            }
        }
    }
}

// ---------------------------------------------------------------------------
// CSR build: count + per-edge rank (atomic), scan (+dinv), atomic-free fill.
// ---------------------------------------------------------------------------
__global__ void count_rank_kernel(const int* __restrict__ dst, int* __restrict__ cnt,
                                  int* __restrict__ rank, int E)
{
    int e = blockIdx.x * 256 + threadIdx.x;
    if (e < E) rank[e] = atomicAdd(&cnt[dst[e]], 1);
}

// 3-phase parallel scan; also emits dinv = rsqrt(deg+1)
__global__ void scan_local(const int* __restrict__ cnt, int* __restrict__ rowptr,
                           int* __restrict__ bsum, float* __restrict__ dinv, int n)
{
    __shared__ int sd[1024];
    const int tid = threadIdx.x;
    const int i = blockIdx.x * 1024 + tid;
    int v = (i < n) ? cnt[i] : 0;
    if (i < n) dinv[i] = rsqrtf((float)v + 1.0f);
    sd[tid] = v;
    __syncthreads();
    for (int off = 1; off < 1024; off <<= 1) {
        int t = (tid >= off) ? sd[tid - off] : 0;
        __syncthreads();
        sd[tid] += t;
        __syncthreads();
    }
    if (i < n) rowptr[i + 1] = sd[tid];
    if (tid == 1023) bsum[blockIdx.x] = sd[1023];
}

__global__ void scan_bsum(int* __restrict__ bsum, int nb)
{
    const int lane = threadIdx.x;  // 64 threads, nb <= 64
    int orig = (lane < nb) ? bsum[lane] : 0;
    int v = orig;
#pragma unroll
    for (int off = 1; off < 64; off <<= 1) {
        int t = __shfl_up(v, off);
        if (lane >= off) v += t;
    }
    if (lane < nb) bsum[lane] = v - orig;  // exclusive prefix
}

__global__ void scan_add(int* __restrict__ rowptr, const int* __restrict__ bsum, int n)
{
    const int i = blockIdx.x * 1024 + threadIdx.x;
    if (i < n) rowptr[i + 1] += bsum[blockIdx.x];
    if (i == 0) rowptr[0] = 0;
}

// atomic-free fill: pos = rowptr[dst] + rank[e]; interleaved (src, w) 8B store
__global__ void fill_kernel(const int* __restrict__ src, const int* __restrict__ dst,
                            const float* __restrict__ dinv, const int* __restrict__ rowptr,
                            const int* __restrict__ rank, int2* __restrict__ csr, int E)
{
    int e = blockIdx.x * 256 + threadIdx.x;
    if (e < E) {
        const int d = dst[e], s = src[e];
        const int pos = rowptr[d] + rank[e];
        int2 p;
        p.x = s;
        p.y = __float_as_int(dinv[s] * dinv[d]);
        csr[pos] = p;
    }
}

// ---------------------------------------------------------------------------
// Aggregation (gather over CSR): ah[n] = h[n]*snorm + sum_e h[src_e]*w_e
// 32 threads/node (float4 lanes), 8 nodes/block, 4-edge unroll for ILP.
// ---------------------------------------------------------------------------
#define FMA4(A, Wt, V) { A.x = fmaf(Wt, V.x, A.x); A.y = fmaf(Wt, V.y, A.y); \
                         A.z = fmaf(Wt, V.z, A.z); A.w = fmaf(Wt, V.w, A.w); }

__global__ __launch_bounds__(256)
void agg_kernel(const float* __restrict__ h, const int2* __restrict__ csr,
                const int* __restrict__ rowptr, const float* __restrict__ dinv,
                float* __restrict__ ah, int n)
{
    const int node = blockIdx.x * 8 + (threadIdx.x >> 5);
    if (node >= n) return;
    const int lane = threadIdx.x & 31;  // float4 index within the 128-wide row
    const float4* __restrict__ h4 = reinterpret_cast<const float4*>(h);

    const float di = dinv[node];
    const float sw = di * di;
    const float4 self = h4[(size_t)node * 32 + lane];
    float4 a0, a1;
    a0.x = self.x * sw; a0.y = self.y * sw; a0.z = self.z * sw; a0.w = self.w * sw;
    a1.x = 0.f; a1.y = 0.f; a1.z = 0.f; a1.w = 0.f;

    const int beg = rowptr[node], end = rowptr[node + 1];
    int s = beg;
    for (; s + 4 <= end; s += 4) {
        const int2 e0 = csr[s+0], e1 = csr[s+1], e2 = csr[s+2], e3 = csr[s+3];
        const float4 v0 = h4[(size_t)e0.x * 32 + lane];
        const float4 v1 = h4[(size_t)e1.x * 32 + lane];
        const float4 v2 = h4[(size_t)e2.x * 32 + lane];
        const float4 v3 = h4[(size_t)e3.x * 32 + lane];
        FMA4(a0, __int_as_float(e0.y), v0); FMA4(a1, __int_as_float(e1.y), v1);
        FMA4(a0, __int_as_float(e2.y), v2); FMA4(a1, __int_as_float(e3.y), v3);
    }
    for (; s < end; ++s) {
        const int2 e0 = csr[s];
        const float4 v = h4[(size_t)e0.x * 32 + lane];
        FMA4(a0, __int_as_float(e0.y), v);
    }
    float4 o;
    o.x = a0.x + a1.x; o.y = a0.y + a1.y; o.z = a0.z + a1.z; o.w = a0.w + a1.w;
    reinterpret_cast<float4*>(ah)[(size_t)node * 32 + lane] = o;
}

// ---------------------------------------------------------------------------
// batch is sorted: per-graph boundaries via binary search
// ---------------------------------------------------------------------------
__global__ void bounds_kernel(const int* __restrict__ batch, int* __restrict__ bound, int n, int g)
{
    const int t = blockIdx.x * blockDim.x + threadIdx.x;
    if (t > g) return;
    int lo = 0, hi = n;
    while (lo < hi) { int mid = (lo + hi) >> 1; if (batch[mid] < t) lo = mid + 1; else hi = mid; }
    bound[t] = lo;
}

// ---------------------------------------------------------------------------
// 2-stage deterministic pooling. Stage 1: 16 fixed chunks per graph.
// ---------------------------------------------------------------------------
__global__ void pool_partial(const float* __restrict__ h, const float* __restrict__ aw,
                             const int* __restrict__ bound, float* __restrict__ ps,
                             float* __restrict__ pm, float* __restrict__ pw)
{
    const int g = blockIdx.x >> 4;
    const int c = blockIdx.x & (POOL_NC - 1);
    const int f = threadIdx.x;  // 128 threads
    const int beg = bound[g], end = bound[g + 1];
    const int len = end - beg;
    const int cbeg = beg + (int)(((long long)len * c) / POOL_NC);
    const int cend = beg + (int)(((long long)len * (c + 1)) / POOL_NC);
    float s = 0.f, m = -FLT_MAX, w = 0.f;
    for (int node = cbeg; node < cend; ++node) {
        const float v = h[(size_t)node * 128 + f];
        const float a = aw[node];
        s += v;
        m = fmaxf(m, v);
        w = fmaf(v, a, w);
    }
    const size_t idx = ((size_t)g * POOL_NC + c) * 128 + f;
    ps[idx] = s; pm[idx] = m; pw[idx] = w;
}

__global__ void pool_final(const float* __restrict__ ps, const float* __restrict__ pm,
                           const float* __restrict__ pw, const int* __restrict__ bound,
                           float* __restrict__ comb)
{
    const int g = blockIdx.x;
    const int f = threadIdx.x;  // 128 threads
    float s = 0.f, m = -FLT_MAX, w = 0.f;
#pragma unroll
    for (int c = 0; c < POOL_NC; ++c) {
        const size_t idx = ((size_t)g * POOL_NC + c) * 128 + f;
        s += ps[idx];
        m = fmaxf(m, pm[idx]);
        w += pw[idx];
    }
    float cn = (float)(bound[g + 1] - bound[g]);
    if (cn < 1.f) cn = 1.f;
    comb[(size_t)g * 512 + f]       = s / cn;
    comb[(size_t)g * 512 + 128 + f] = m;
    comb[(size_t)g * 512 + 256 + f] = s / cn;
    comb[(size_t)g * 512 + 384 + f] = w / cn;
}

// ---------------------------------------------------------------------------
// classifier head GEMM: grid = G * (M/64); block 256 = 64 cols x 4 k-quarters.
// ---------------------------------------------------------------------------
template<int K, int M, bool DO_BN, bool DO_GELU>
__global__ __launch_bounds__(256)
void rowgemm2(const float* __restrict__ X, const float* __restrict__ W,
              const float* __restrict__ bias, const float* __restrict__ gam,
              const float* __restrict__ beta, float* __restrict__ Y)
{
    constexpr int NC = M / 64;
    constexpr int KQ = K / 4;
    const int row = blockIdx.x / NC;
    const int lane = threadIdx.x & 63;
    const int c = (blockIdx.x % NC) * 64 + lane;
    const int q = threadIdx.x >> 6;  // k-quarter 0..3

    const float* __restrict__ xq = X + (size_t)row * K + q * KQ;
    const float* __restrict__ wq = W + (size_t)(q * KQ) * M + c;

    float a0 = 0.f, a1 = 0.f, a2 = 0.f, a3 = 0.f;
#pragma unroll 4
    for (int k = 0; k < KQ; k += 4) {
        const float4 xv = *reinterpret_cast<const float4*>(xq + k);
        a0 = fmaf(xv.x, wq[(size_t)(k + 0) * M], a0);
        a1 = fmaf(xv.y, wq[(size_t)(k + 1) * M], a1);
        a2 = fmaf(xv.z, wq[(size_t)(k + 2) * M], a2);
        a3 = fmaf(xv.w, wq[(size_t)(k + 3) * M], a3);
    }
    __shared__ float part[4][64];
    part[q][lane] = (a0 + a1) + (a2 + a3);
    __syncthreads();
    if (q == 0) {
        float v = (part[0][lane] + part[1][lane]) + (part[2][lane] + part[3][lane]);
        if (DO_BN) { const float g = gam[c]; const float sc = g * BNS_F; v = v * sc + (bias[c] * sc + beta[c]); }
        else       { v = v + bias[c]; }
        if (DO_GELU) v = gelu_f(v);
        Y[(size_t)row * M + c] = v;
    }
}

// final layer: [G,64] @ [64,4] + bias; one wave per row, shuffle reduce
__global__ void rowgemm_final(const float* __restrict__ X, const float* __restrict__ W,
                              const float* __restrict__ bias, float* __restrict__ Y)
{
    const int row = blockIdx.x;
    const int lane = threadIdx.x;  // 64
    const float xv = X[(size_t)row * 64 + lane];
    const float4 wr = *reinterpret_cast<const float4*>(W + lane * 4);
    float a0 = xv * wr.x, a1 = xv * wr.y, a2 = xv * wr.z, a3 = xv * wr.w;
#pragma unroll
    for (int off = 32; off; off >>= 1) {
        a0 += __shfl_xor(a0, off);
        a1 += __shfl_xor(a1, off);
        a2 += __shfl_xor(a2, off);
        a3 += __shfl_xor(a3, off);
    }
    if (lane == 0) {
        Y[(size_t)row * 4 + 0] = a0 + bias[0];
        Y[(size_t)row * 4 + 1] = a1 + bias[1];
        Y[(size_t)row * 4 + 2] = a2 + bias[2];
        Y[(size_t)row * 4 + 3] = a3 + bias[3];
    }
}

// ---------------------------------------------------------------------------
extern "C" void kernel_launch(void* const* d_in, const int* in_sizes, int n_in,
                              void* d_out, int out_size, void* d_ws, size_t ws_size,
                              hipStream_t stream)
{
    const float* x     = (const float*)d_in[0];
    const int*   ei    = (const int*)d_in[1];
    const int*   batch = (const int*)d_in[2];
    const float* W1  = (const float*)d_in[3];
    const float* b1  = (const float*)d_in[4];
    const float* g1  = (const float*)d_in[5];
    const float* be1 = (const float*)d_in[6];
    const float* W2  = (const float*)d_in[7];
    const float* b2  = (const float*)d_in[8];
    const float* g2  = (const float*)d_in[9];
    const float* be2 = (const float*)d_in[10];
    const float* Wg  = (const float*)d_in[11];
    const float* bg  = (const float*)d_in[12];
    const float* gg  = (const float*)d_in[13];
    const float* bgg = (const float*)d_in[14];
    const float* Wa1 = (const float*)d_in[15];
    const float* ba1 = (const float*)d_in[16];
    const float* Wa2 = (const float*)d_in[17];
    const float* ba2 = (const float*)d_in[18];
    const float* Wc1 = (const float*)d_in[19];
    const float* bc1 = (const float*)d_in[20];
    const float* gc1 = (const float*)d_in[21];
    const float* bec1= (const float*)d_in[22];
    const float* Wc2 = (const float*)d_in[23];
    const float* bc2 = (const float*)d_in[24];
    const float* gc2 = (const float*)d_in[25];
    const float* bec2= (const float*)d_in[26];
    const float* Wc3 = (const float*)d_in[27];
    const float* bc3 = (const float*)d_in[28];
    const float* gc3 = (const float*)d_in[29];
    const float* bec3= (const float*)d_in[30];
    const float* Wc4 = (const float*)d_in[31];
    const float* bc4 = (const float*)d_in[32];
    float* out = (float*)d_out;

    const int N = in_sizes[0] / 128;
    const int E = in_sizes[1] / 2;
    const int G = GGRAPHS;

    // workspace carve-up
    size_t off = 0;
    auto alloc = [&](size_t bytes) -> void* {
        void* p = (char*)d_ws + off;
        off += (bytes + 255) & ~(size_t)255;
        return p;
    };
    float* hA     = (float*)alloc((size_t)N * 128 * 4);
    float* hB     = (float*)alloc((size_t)N * 128 * 4);
    float* aw     = (float*)alloc((size_t)N * 4);
    float* dinv   = (float*)alloc((size_t)N * 4);
    int*   cnt    = (int*)alloc((size_t)N * 4);
    int*   rank   = (int*)alloc((size_t)E * 4);
    int*   rowptr = (int*)alloc((size_t)(N + 1) * 4);
    int*   bsum   = (int*)alloc(64 * 4);
    int2*  csr    = (int2*)alloc((size_t)E * 8);
    int*   bound  = (int*)alloc((size_t)(G + 1) * 4);
    float* comb   = (float*)alloc((size_t)G * 512 * 4);
    float* ps     = (float*)alloc((size_t)G * POOL_NC * 128 * 4);
    float* pm     = (float*)alloc((size_t)G * POOL_NC * 128 * 4);
    float* pw     = (float*)alloc((size_t)G * POOL_NC * 128 * 4);
    float* z1     = (float*)alloc((size_t)G * 256 * 4);
    float* z2     = (float*)alloc((size_t)G * 128 * 4);
    float* z3     = (float*)alloc((size_t)G * 64 * 4);
    (void)ws_size;

    const int* e_src = ei;
    const int* e_dst = ei + E;

    // ---- CSR build over dst (reused by all 3 GCN layers) ----
    hipMemsetAsync(cnt, 0, (size_t)N * 4, stream);
    count_rank_kernel<<<(E + 255) / 256, 256, 0, stream>>>(e_dst, cnt, rank, E);
    const int nb = (N + 1023) / 1024;
    scan_local<<<nb, 1024, 0, stream>>>(cnt, rowptr, bsum, dinv, N);
    scan_bsum<<<1, 64, 0, stream>>>(bsum, nb);
    scan_add<<<nb, 1024, 0, stream>>>(rowptr, bsum, N);
    fill_kernel<<<(E + 255) / 256, 256, 0, stream>>>(e_src, e_dst, dinv, rowptr, rank, csr, E);

    const int gblocks = (N + 127) / 128;

    // ---- input projection ----
    gemm_fused<128, true, true, false, false><<<gblocks, 256, 0, stream>>>(
        x,  W1, b1, g1, be1, nullptr, hA, nullptr, nullptr, nullptr, N);
    gemm_fused<128, true, true, false, false><<<gblocks, 256, 0, stream>>>(
        hA, W2, b2, g2, be2, nullptr, hA, nullptr, nullptr, nullptr, N);

    // ---- GCN layers: aggregate-then-transform (linearity) ----
    for (int l = 0; l < 3; ++l) {
        agg_kernel<<<(N + 7) / 8, 256, 0, stream>>>(hA, csr, rowptr, dinv, hB, N);
        gemm_fused<128, true, true, true, false><<<gblocks, 256, 0, stream>>>(
            hB, Wg + (size_t)l * 128 * 128, bg + (size_t)l * 128,
            gg + (size_t)l * 128, bgg + (size_t)l * 128, hA, hA, nullptr, nullptr, nullptr, N);
    }

    // ---- attention weights (fused: gelu(h@Wa1+ba1)@Wa2+ba2 -> tanh) ----
    gemm_fused<64, false, true, false, true><<<gblocks, 256, 0, stream>>>(
        hA, Wa1, ba1, nullptr, nullptr, nullptr, nullptr, Wa2, ba2, aw, N);

    // ---- pooling ----
    bounds_kernel<<<1, 256, 0, stream>>>(batch, bound, N, G);
    pool_partial<<<G * POOL_NC, 128, 0, stream>>>(hA, aw, bound, ps, pm, pw);
    pool_final<<<G, 128, 0, stream>>>(ps, pm, pw, bound, comb);

    // ---- classifier head ----
    rowgemm2<512, 256, true, true><<<G * 4, 256, 0, stream>>>(comb, Wc1, bc1, gc1, bec1, z1);
    rowgemm2<256, 128, true, true><<<G * 2, 256, 0, stream>>>(z1, Wc2, bc2, gc2, bec2, z2);
    rowgemm2<128, 64,  true, true><<<G * 1, 256, 0, stream>>>(z2, Wc3, bc3, gc3, bec3, z3);
    rowgemm_final<<<G, 64, 0, stream>>>(z3, Wc4, bc4, out);
}

// Round 5
// 495.648 us; speedup vs baseline: 2.0501x; 1.0911x over previous
//
#include <hip/hip_runtime.h>
#include <hip/hip_bf16.h>
#include <float.h>

// ---------------------------------------------------------------------------
// ImprovedTransformerGNN: fp32 compute, bf16 gather table for aggregation.
// N=50000, E=600000, H=128, IN=128, C=4, L=3, G=128.
// R5: GEMMs feeding an aggregation also emit bf16 h (RNE); agg gathers 256B
//     bf16 rows (halves random-gather traffic), accumulates fp32.
// ---------------------------------------------------------------------------

#define GGRAPHS 128
#define POOL_NC 16

__device__ __forceinline__ float gelu_f(float x) {
    return 0.5f * x * (1.0f + erff(x * 0.7071067811865476f));
}

__device__ __forceinline__ unsigned short f2bf(float f) {  // RNE, finite inputs
    unsigned int u = __float_as_uint(f);
    unsigned int r = (u + 0x7FFFu + ((u >> 16) & 1u)) >> 16;
    return (unsigned short)r;
}

__device__ __forceinline__ float bf2f(unsigned short u) {
    return __uint_as_float(((unsigned int)u) << 16);
}

static constexpr float BNS_F = 0.99999500003749968f;  // 1/sqrt(1+1e-5)

// ---------------------------------------------------------------------------
// Fused GEMM: Y[nrows,M] = act( (X[nrows,128] @ W[128,M]) * sc + bi ) (+resid)
// Block: 256 threads, 128 rows; colgrp=tid&15 (16 x CPT cols), rowgrp=tid>>4
// (16 x 8 rows). Per kk: 2 LDS b128 reads reused across 8 rows -> VALU-bound.
// In-place X==Y safe. DO_AW: emit aw instead of Y. DO_BF16: also write bf16 Y.
// ---------------------------------------------------------------------------
template<int M, bool DO_BN, bool DO_GELU, bool DO_RES, bool DO_AW, bool DO_BF16>
__global__ __launch_bounds__(256, 2)
void gemm_fused(const float* __restrict__ X, const float* __restrict__ W,
                const float* __restrict__ bias, const float* __restrict__ gam,
                const float* __restrict__ beta, const float* __restrict__ resid,
                float* __restrict__ Y, ushort4* __restrict__ Ybf,
                const float* __restrict__ Wa2, const float* __restrict__ ba2,
                float* __restrict__ awout, int nrows)
{
    constexpr int CPT = M / 16;   // 8 (M=128) or 4 (M=64)
    constexpr int NF4 = M / 4;    // float4 per k-row
    __shared__ float4 Ws[128 * NF4];   // 64KB / 32KB

    const int tid = threadIdx.x;
    const float4* W4 = reinterpret_cast<const float4*>(W);
#pragma unroll
    for (int i = 0; i < (128 * NF4) / 256; ++i)
        Ws[tid + i * 256] = W4[tid + i * 256];
    __syncthreads();

    const int colgrp = tid & 15;
    const int rowgrp = tid >> 4;
    const int r0 = blockIdx.x * 128 + rowgrp * 8;

    float acc[8][CPT];
#pragma unroll
    for (int i = 0; i < 8; ++i)
#pragma unroll
        for (int j = 0; j < CPT; ++j) acc[i][j] = 0.f;

    const float4* xp[8];
#pragma unroll
    for (int i = 0; i < 8; ++i) {
        int r = r0 + i; if (r >= nrows) r = nrows - 1;
        xp[i] = reinterpret_cast<const float4*>(X + (size_t)r * 128);
    }
    float4 xv[8];
#pragma unroll
    for (int i = 0; i < 8; ++i) xv[i] = xp[i][0];

    for (int k4 = 0; k4 < 32; ++k4) {
        float4 xn[8];
        if (k4 < 31) {
#pragma unroll
            for (int i = 0; i < 8; ++i) xn[i] = xp[i][k4 + 1];
        }
#pragma unroll
        for (int kk = 0; kk < 4; ++kk) {
            const int k = k4 * 4 + kk;
            const float4 w0 = Ws[k * NF4 + colgrp];
            float4 w1;
            if (CPT == 8) w1 = Ws[k * NF4 + 16 + colgrp];
#pragma unroll
            for (int i = 0; i < 8; ++i) {
                const float xs = reinterpret_cast<const float*>(&xv[i])[kk];
                acc[i][0] = fmaf(xs, w0.x, acc[i][0]);
                acc[i][1] = fmaf(xs, w0.y, acc[i][1]);
                acc[i][2] = fmaf(xs, w0.z, acc[i][2]);
                acc[i][3] = fmaf(xs, w0.w, acc[i][3]);
                if (CPT == 8) {
                    acc[i][4] = fmaf(xs, w1.x, acc[i][4]);
                    acc[i][5] = fmaf(xs, w1.y, acc[i][5]);
                    acc[i][6] = fmaf(xs, w1.z, acc[i][6]);
                    acc[i][7] = fmaf(xs, w1.w, acc[i][7]);
                }
            }
        }
        if (k4 < 31) {
#pragma unroll
            for (int i = 0; i < 8; ++i) xv[i] = xn[i];
        }
    }

    // epilogue: per-column scale/bias (BN folded), gelu, residual / aw
    float scA[4], biA[4], scB[4], biB[4];
#pragma unroll
    for (int j = 0; j < 4; ++j) {
        const int c = 4 * colgrp + j;
        if (DO_BN) { float g = gam[c]; scA[j] = g * BNS_F; biA[j] = bias[c] * scA[j] + beta[c]; }
        else       { scA[j] = 1.f;     biA[j] = bias[c]; }
        if (CPT == 8) {
            const int c2 = 64 + 4 * colgrp + j;
            if (DO_BN) { float g = gam[c2]; scB[j] = g * BNS_F; biB[j] = bias[c2] * scB[j] + beta[c2]; }
            else       { scB[j] = 1.f;      biB[j] = bias[c2]; }
        }
    }

    if (DO_AW) {
        float wa[4];
#pragma unroll
        for (int j = 0; j < 4; ++j) wa[j] = Wa2[4 * colgrp + j];
        const float ba2v = ba2[0];
#pragma unroll
        for (int i = 0; i < 8; ++i) {
            float p = 0.f;
#pragma unroll
            for (int j = 0; j < 4; ++j) {
                float v = acc[i][j] * scA[j] + biA[j];
                if (DO_GELU) v = gelu_f(v);
                p = fmaf(v, wa[j], p);
            }
            p += __shfl_xor(p, 1);
            p += __shfl_xor(p, 2);
            p += __shfl_xor(p, 4);
            p += __shfl_xor(p, 8);
            const int r = r0 + i;
            if (colgrp == 0 && r < nrows) awout[r] = tanhf(p + ba2v);
        }
        return;
    }

#pragma unroll
    for (int i = 0; i < 8; ++i) {
        const int r = r0 + i;
        if (r < nrows) {
            float4 o0; float* o0f = reinterpret_cast<float*>(&o0);
#pragma unroll
            for (int j = 0; j < 4; ++j) {
                float v = acc[i][j] * scA[j] + biA[j];
                if (DO_GELU) v = gelu_f(v);
                if (DO_RES) v += resid[(size_t)r * M + 4 * colgrp + j];
                o0f[j] = v;
            }
            *reinterpret_cast<float4*>(Y + (size_t)r * M + 4 * colgrp) = o0;
            if (DO_BF16) {
                ushort4 q;
                q.x = f2bf(o0f[0]); q.y = f2bf(o0f[1]); q.z = f2bf(o0f[2]); q.w = f2bf(o0f[3]);
                Ybf[(size_t)r * 32 + colgrp] = q;
            }
            if (CPT == 8) {
                float4 o1; float* o1f = reinterpret_cast<float*>(&o1);
#pragma unroll
                for (int j = 0; j < 4; ++j) {
                    float v = acc[i][4 + j] * scB[j] + biB[j];
                    if (DO_GELU) v = gelu_f(v);
                    if (DO_RES) v += resid[(size_t)r * M + 64 + 4 * colgrp + j];
                    o1f[j] = v;
                }
                *reinterpret_cast<float4*>(Y + (size_t)r * M + 64 + 4 * colgrp) = o1;
                if (DO_BF16) {
                    ushort4 q;
                    q.x = f2bf(o1f[0]); q.y = f2bf(o1f[1]); q.z = f2bf(o1f[2]); q.w = f2bf(o1f[3]);
                    Ybf[(size_t)r * 32 + 16 + colgrp] = q;
                }
            }
        }
    }
}

// ---------------------------------------------------------------------------
// CSR build: count + per-edge rank (atomic), scan (+dinv), atomic-free fill.
// ---------------------------------------------------------------------------
__global__ void count_rank_kernel(const int* __restrict__ dst, int* __restrict__ cnt,
                                  int* __restrict__ rank, int E)
{
    int e = blockIdx.x * 256 + threadIdx.x;
    if (e < E) rank[e] = atomicAdd(&cnt[dst[e]], 1);
}

// 3-phase parallel scan; also emits dinv = rsqrt(deg+1)
__global__ void scan_local(const int* __restrict__ cnt, int* __restrict__ rowptr,
                           int* __restrict__ bsum, float* __restrict__ dinv, int n)
{
    __shared__ int sd[1024];
    const int tid = threadIdx.x;
    const int i = blockIdx.x * 1024 + tid;
    int v = (i < n) ? cnt[i] : 0;
    if (i < n) dinv[i] = rsqrtf((float)v + 1.0f);
    sd[tid] = v;
    __syncthreads();
    for (int off = 1; off < 1024; off <<= 1) {
        int t = (tid >= off) ? sd[tid - off] : 0;
        __syncthreads();
        sd[tid] += t;
        __syncthreads();
    }
    if (i < n) rowptr[i + 1] = sd[tid];
    if (tid == 1023) bsum[blockIdx.x] = sd[1023];
}

__global__ void scan_bsum(int* __restrict__ bsum, int nb)
{
    const int lane = threadIdx.x;  // 64 threads, nb <= 64
    int orig = (lane < nb) ? bsum[lane] : 0;
    int v = orig;
#pragma unroll
    for (int off = 1; off < 64; off <<= 1) {
        int t = __shfl_up(v, off);
        if (lane >= off) v += t;
    }
    if (lane < nb) bsum[lane] = v - orig;  // exclusive prefix
}

__global__ void scan_add(int* __restrict__ rowptr, const int* __restrict__ bsum, int n)
{
    const int i = blockIdx.x * 1024 + threadIdx.x;
    if (i < n) rowptr[i + 1] += bsum[blockIdx.x];
    if (i == 0) rowptr[0] = 0;
}

// atomic-free fill: pos = rowptr[dst] + rank[e]; interleaved (src, w) 8B store
__global__ void fill_kernel(const int* __restrict__ src, const int* __restrict__ dst,
                            const float* __restrict__ dinv, const int* __restrict__ rowptr,
                            const int* __restrict__ rank, int2* __restrict__ csr, int E)
{
    int e = blockIdx.x * 256 + threadIdx.x;
    if (e < E) {
        const int d = dst[e], s = src[e];
        const int pos = rowptr[d] + rank[e];
        int2 p;
        p.x = s;
        p.y = __float_as_int(dinv[s] * dinv[d]);
        csr[pos] = p;
    }
}

// ---------------------------------------------------------------------------
// Aggregation (gather over CSR, bf16 rows): ah = h*snorm + sum h[src]*w
// 32 threads/node (ushort4 lanes = 8B), 8 nodes/block, 4-edge unroll.
// fp32 accumulate.
// ---------------------------------------------------------------------------
#define FMAB(A, Wt, U) { A.x = fmaf(Wt, bf2f(U.x), A.x); A.y = fmaf(Wt, bf2f(U.y), A.y); \
                         A.z = fmaf(Wt, bf2f(U.z), A.z); A.w = fmaf(Wt, bf2f(U.w), A.w); }

__global__ __launch_bounds__(256)
void agg_kernel(const ushort4* __restrict__ hb, const int2* __restrict__ csr,
                const int* __restrict__ rowptr, const float* __restrict__ dinv,
                float* __restrict__ ah, int n)
{
    const int node = blockIdx.x * 8 + (threadIdx.x >> 5);
    if (node >= n) return;
    const int lane = threadIdx.x & 31;  // ushort4 index within the 128-wide row

    const float di = dinv[node];
    const float sw = di * di;
    const ushort4 sv = hb[(size_t)node * 32 + lane];
    float4 a0, a1;
    a0.x = bf2f(sv.x) * sw; a0.y = bf2f(sv.y) * sw;
    a0.z = bf2f(sv.z) * sw; a0.w = bf2f(sv.w) * sw;
    a1.x = 0.f; a1.y = 0.f; a1.z = 0.f; a1.w = 0.f;

    const int beg = rowptr[node], end = rowptr[node + 1];
    int s = beg;
    for (; s + 4 <= end; s += 4) {
        const int2 e0 = csr[s+0], e1 = csr[s+1], e2 = csr[s+2], e3 = csr[s+3];
        const ushort4 v0 = hb[(size_t)e0.x * 32 + lane];
        const ushort4 v1 = hb[(size_t)e1.x * 32 + lane];
        const ushort4 v2 = hb[(size_t)e2.x * 32 + lane];
        const ushort4 v3 = hb[(size_t)e3.x * 32 + lane];
        FMAB(a0, __int_as_float(e0.y), v0); FMAB(a1, __int_as_float(e1.y), v1);
        FMAB(a0, __int_as_float(e2.y), v2); FMAB(a1, __int_as_float(e3.y), v3);
    }
    for (; s < end; ++s) {
        const int2 e0 = csr[s];
        const ushort4 v = hb[(size_t)e0.x * 32 + lane];
        FMAB(a0, __int_as_float(e0.y), v);
    }
    float4 o;
    o.x = a0.x + a1.x; o.y = a0.y + a1.y; o.z = a0.z + a1.z; o.w = a0.w + a1.w;
    // ah row layout: lane covers cols [4*lane .. 4*lane+3]
    reinterpret_cast<float4*>(ah)[(size_t)node * 32 + lane] = o;
}

// ---------------------------------------------------------------------------
// batch is sorted: per-graph boundaries via binary search
// ---------------------------------------------------------------------------
__global__ void bounds_kernel(const int* __restrict__ batch, int* __restrict__ bound, int n, int g)
{
    const int t = blockIdx.x * blockDim.x + threadIdx.x;
    if (t > g) return;
    int lo = 0, hi = n;
    while (lo < hi) { int mid = (lo + hi) >> 1; if (batch[mid] < t) lo = mid + 1; else hi = mid; }
    bound[t] = lo;
}

// ---------------------------------------------------------------------------
// 2-stage deterministic pooling. Stage 1: 16 fixed chunks per graph.
// ---------------------------------------------------------------------------
__global__ void pool_partial(const float* __restrict__ h, const float* __restrict__ aw,
                             const int* __restrict__ bound, float* __restrict__ ps,
                             float* __restrict__ pm, float* __restrict__ pw)
{
    const int g = blockIdx.x >> 4;
    const int c = blockIdx.x & (POOL_NC - 1);
    const int f = threadIdx.x;  // 128 threads
    const int beg = bound[g], end = bound[g + 1];
    const int len = end - beg;
    const int cbeg = beg + (int)(((long long)len * c) / POOL_NC);
    const int cend = beg + (int)(((long long)len * (c + 1)) / POOL_NC);
    float s = 0.f, m = -FLT_MAX, w = 0.f;
    for (int node = cbeg; node < cend; ++node) {
        const float v = h[(size_t)node * 128 + f];
        const float a = aw[node];
        s += v;
        m = fmaxf(m, v);
        w = fmaf(v, a, w);
    }
    const size_t idx = ((size_t)g * POOL_NC + c) * 128 + f;
    ps[idx] = s; pm[idx] = m; pw[idx] = w;
}

__global__ void pool_final(const float* __restrict__ ps, const float* __restrict__ pm,
                           const float* __restrict__ pw, const int* __restrict__ bound,
                           float* __restrict__ comb)
{
    const int g = blockIdx.x;
    const int f = threadIdx.x;  // 128 threads
    float s = 0.f, m = -FLT_MAX, w = 0.f;
#pragma unroll
    for (int c = 0; c < POOL_NC; ++c) {
        const size_t idx = ((size_t)g * POOL_NC + c) * 128 + f;
        s += ps[idx];
        m = fmaxf(m, pm[idx]);
        w += pw[idx];
    }
    float cn = (float)(bound[g + 1] - bound[g]);
    if (cn < 1.f) cn = 1.f;
    comb[(size_t)g * 512 + f]       = s / cn;
    comb[(size_t)g * 512 + 128 + f] = m;
    comb[(size_t)g * 512 + 256 + f] = s / cn;
    comb[(size_t)g * 512 + 384 + f] = w / cn;
}

// ---------------------------------------------------------------------------
// classifier head GEMM: grid = G * (M/64); block 256 = 64 cols x 4 k-quarters.
// ---------------------------------------------------------------------------
template<int K, int M, bool DO_BN, bool DO_GELU>
__global__ __launch_bounds__(256)
void rowgemm2(const float* __restrict__ X, const float* __restrict__ W,
              const float* __restrict__ bias, const float* __restrict__ gam,
              const float* __restrict__ beta, float* __restrict__ Y)
{
    constexpr int NC = M / 64;
    constexpr int KQ = K / 4;
    const int row = blockIdx.x / NC;
    const int lane = threadIdx.x & 63;
    const int c = (blockIdx.x % NC) * 64 + lane;
    const int q = threadIdx.x >> 6;  // k-quarter 0..3

    const float* __restrict__ xq = X + (size_t)row * K + q * KQ;
    const float* __restrict__ wq = W + (size_t)(q * KQ) * M + c;

    float a0 = 0.f, a1 = 0.f, a2 = 0.f, a3 = 0.f;
#pragma unroll 4
    for (int k = 0; k < KQ; k += 4) {
        const float4 xv = *reinterpret_cast<const float4*>(xq + k);
        a0 = fmaf(xv.x, wq[(size_t)(k + 0) * M], a0);
        a1 = fmaf(xv.y, wq[(size_t)(k + 1) * M], a1);
        a2 = fmaf(xv.z, wq[(size_t)(k + 2) * M], a2);
        a3 = fmaf(xv.w, wq[(size_t)(k + 3) * M], a3);
    }
    __shared__ float part[4][64];
    part[q][lane] = (a0 + a1) + (a2 + a3);
    __syncthreads();
    if (q == 0) {
        float v = (part[0][lane] + part[1][lane]) + (part[2][lane] + part[3][lane]);
        if (DO_BN) { const float g = gam[c]; const float sc = g * BNS_F; v = v * sc + (bias[c] * sc + beta[c]); }
        else       { v = v + bias[c]; }
        if (DO_GELU) v = gelu_f(v);
        Y[(size_t)row * M + c] = v;
    }
}

// final layer: [G,64] @ [64,4] + bias; one wave per row, shuffle reduce
__global__ void rowgemm_final(const float* __restrict__ X, const float* __restrict__ W,
                              const float* __restrict__ bias, float* __restrict__ Y)
{
    const int row = blockIdx.x;
    const int lane = threadIdx.x;  // 64
    const float xv = X[(size_t)row * 64 + lane];
    const float4 wr = *reinterpret_cast<const float4*>(W + lane * 4);
    float a0 = xv * wr.x, a1 = xv * wr.y, a2 = xv * wr.z, a3 = xv * wr.w;
#pragma unroll
    for (int off = 32; off; off >>= 1) {
        a0 += __shfl_xor(a0, off);
        a1 += __shfl_xor(a1, off);
        a2 += __shfl_xor(a2, off);
        a3 += __shfl_xor(a3, off);
    }
    if (lane == 0) {
        Y[(size_t)row * 4 + 0] = a0 + bias[0];
        Y[(size_t)row * 4 + 1] = a1 + bias[1];
        Y[(size_t)row * 4 + 2] = a2 + bias[2];
        Y[(size_t)row * 4 + 3] = a3 + bias[3];
    }
}

// ---------------------------------------------------------------------------
extern "C" void kernel_launch(void* const* d_in, const int* in_sizes, int n_in,
                              void* d_out, int out_size, void* d_ws, size_t ws_size,
                              hipStream_t stream)
{
    const float* x     = (const float*)d_in[0];
    const int*   ei    = (const int*)d_in[1];
    const int*   batch = (const int*)d_in[2];
    const float* W1  = (const float*)d_in[3];
    const float* b1  = (const float*)d_in[4];
    const float* g1  = (const float*)d_in[5];
    const float* be1 = (const float*)d_in[6];
    const float* W2  = (const float*)d_in[7];
    const float* b2  = (const float*)d_in[8];
    const float* g2  = (const float*)d_in[9];
    const float* be2 = (const float*)d_in[10];
    const float* Wg  = (const float*)d_in[11];
    const float* bg  = (const float*)d_in[12];
    const float* gg  = (const float*)d_in[13];
    const float* bgg = (const float*)d_in[14];
    const float* Wa1 = (const float*)d_in[15];
    const float* ba1 = (const float*)d_in[16];
    const float* Wa2 = (const float*)d_in[17];
    const float* ba2 = (const float*)d_in[18];
    const float* Wc1 = (const float*)d_in[19];
    const float* bc1 = (const float*)d_in[20];
    const float* gc1 = (const float*)d_in[21];
    const float* bec1= (const float*)d_in[22];
    const float* Wc2 = (const float*)d_in[23];
    const float* bc2 = (const float*)d_in[24];
    const float* gc2 = (const float*)d_in[25];
    const float* bec2= (const float*)d_in[26];
    const float* Wc3 = (const float*)d_in[27];
    const float* bc3 = (const float*)d_in[28];
    const float* gc3 = (const float*)d_in[29];
    const float* bec3= (const float*)d_in[30];
    const float* Wc4 = (const float*)d_in[31];
    const float* bc4 = (const float*)d_in[32];
    float* out = (float*)d_out;

    const int N = in_sizes[0] / 128;
    const int E = in_sizes[1] / 2;
    const int G = GGRAPHS;

    // workspace carve-up
    size_t off = 0;
    auto alloc = [&](size_t bytes) -> void* {
        void* p = (char*)d_ws + off;
        off += (bytes + 255) & ~(size_t)255;
        return p;
    };
    float*   hA     = (float*)alloc((size_t)N * 128 * 4);
    float*   hB     = (float*)alloc((size_t)N * 128 * 4);
    ushort4* hbf    = (ushort4*)alloc((size_t)N * 128 * 2);
    float*   aw     = (float*)alloc((size_t)N * 4);
    float*   dinv   = (float*)alloc((size_t)N * 4);
    int*     cnt    = (int*)alloc((size_t)N * 4);
    int*     rank   = (int*)alloc((size_t)E * 4);
    int*     rowptr = (int*)alloc((size_t)(N + 1) * 4);
    int*     bsum   = (int*)alloc(64 * 4);
    int2*    csr    = (int2*)alloc((size_t)E * 8);
    int*     bound  = (int*)alloc((size_t)(G + 1) * 4);
    float*   comb   = (float*)alloc((size_t)G * 512 * 4);
    float*   ps     = (float*)alloc((size_t)G * POOL_NC * 128 * 4);
    float*   pm     = (float*)alloc((size_t)G * POOL_NC * 128 * 4);
    float*   pw     = (float*)alloc((size_t)G * POOL_NC * 128 * 4);
    float*   z1     = (float*)alloc((size_t)G * 256 * 4);
    float*   z2     = (float*)alloc((size_t)G * 128 * 4);
    float*   z3     = (float*)alloc((size_t)G * 64 * 4);
    (void)ws_size;

    const int* e_src = ei;
    const int* e_dst = ei + E;

    // ---- CSR build over dst (reused by all 3 GCN layers) ----
    hipMemsetAsync(cnt, 0, (size_t)N * 4, stream);
    count_rank_kernel<<<(E + 255) / 256, 256, 0, stream>>>(e_dst, cnt, rank, E);
    const int nb = (N + 1023) / 1024;
    scan_local<<<nb, 1024, 0, stream>>>(cnt, rowptr, bsum, dinv, N);
    scan_bsum<<<1, 64, 0, stream>>>(bsum, nb);
    scan_add<<<nb, 1024, 0, stream>>>(rowptr, bsum, N);
    fill_kernel<<<(E + 255) / 256, 256, 0, stream>>>(e_src, e_dst, dinv, rowptr, rank, csr, E);

    const int gblocks = (N + 127) / 128;

    // ---- input projection ----
    gemm_fused<128, true, true, false, false, false><<<gblocks, 256, 0, stream>>>(
        x,  W1, b1, g1, be1, nullptr, hA, nullptr, nullptr, nullptr, nullptr, N);
    gemm_fused<128, true, true, false, false, true><<<gblocks, 256, 0, stream>>>(
        hA, W2, b2, g2, be2, nullptr, hA, hbf, nullptr, nullptr, nullptr, N);

    // ---- GCN layers: aggregate-then-transform (linearity) ----
    for (int l = 0; l < 3; ++l) {
        agg_kernel<<<(N + 7) / 8, 256, 0, stream>>>(hbf, csr, rowptr, dinv, hB, N);
        if (l < 2) {
            gemm_fused<128, true, true, true, false, true><<<gblocks, 256, 0, stream>>>(
                hB, Wg + (size_t)l * 128 * 128, bg + (size_t)l * 128,
                gg + (size_t)l * 128, bgg + (size_t)l * 128, hA, hA, hbf,
                nullptr, nullptr, nullptr, N);
        } else {
            gemm_fused<128, true, true, true, false, false><<<gblocks, 256, 0, stream>>>(
                hB, Wg + (size_t)l * 128 * 128, bg + (size_t)l * 128,
                gg + (size_t)l * 128, bgg + (size_t)l * 128, hA, hA, nullptr,
                nullptr, nullptr, nullptr, N);
        }
    }

    // ---- attention weights (fused: gelu(h@Wa1+ba1)@Wa2+ba2 -> tanh) ----
    gemm_fused<64, false, true, false, true, false><<<gblocks, 256, 0, stream>>>(
        hA, Wa1, ba1, nullptr, nullptr, nullptr, nullptr, nullptr, Wa2, ba2, aw, N);

    // ---- pooling ----
    bounds_kernel<<<1, 256, 0, stream>>>(batch, bound, N, G);
    pool_partial<<<G * POOL_NC, 128, 0, stream>>>(hA, aw, bound, ps, pm, pw);
    pool_final<<<G, 128, 0, stream>>>(ps, pm, pw, bound, comb);

    // ---- classifier head ----
    rowgemm2<512, 256, true, true><<<G * 4, 256, 0, stream>>>(comb, Wc1, bc1, gc1, bec1, z1);
    rowgemm2<256, 128, true, true><<<G * 2, 256, 0, stream>>>(z1, Wc2, bc2, gc2, bec2, z2);
    rowgemm2<128, 64,  true, true><<<G * 1, 256, 0, stream>>>(z2, Wc3, bc3, gc3, bec3, z3);
    rowgemm_final<<<G, 64, 0, stream>>>(z3, Wc4, bc4, out);
}